// Round 6
// baseline (334.300 us; speedup 1.0000x reference)
//
#include <hip/hip_runtime.h>

typedef unsigned short u16;
typedef unsigned int u32;

#define S 2048
#define HID 2048
#define NH 16
#define NKV 4
#define D 128
#define QKVP 3072  // QKV buffer pitch (Q|K|V concat per row)
// 1/sqrt(128) * log2(e): scores come out of QK^T already in log2 domain
#define QSCALE (0.08838834764831845f * 1.4426950408889634f)
#define NEG_INF -3.0e38f

typedef __attribute__((ext_vector_type(8))) short short8;  // 8 bf16 = 4 VGPRs
typedef __attribute__((ext_vector_type(4))) float f32x4;

__device__ __forceinline__ float bf2f(u16 u) {
  union { u32 i; float f; } c; c.i = ((u32)u) << 16; return c.f;
}
__device__ __forceinline__ u16 f2bf(float f) {
  union { float f; u32 i; } c; c.f = f;
  u32 x = c.i;
  u32 r = x + 0x7fffu + ((x >> 16) & 1u);  // RNE
  return (u16)(r >> 16);
}

#if __has_builtin(__builtin_amdgcn_exp2f)
__device__ __forceinline__ float exp2_hw(float x) { return __builtin_amdgcn_exp2f(x); }
#else
__device__ __forceinline__ float exp2_hw(float x) { return exp2f(x); }
#endif

// packed f32x2 -> bf16x2 (RNE), single VOP3
__device__ __forceinline__ u32 cvt_pk_bf16(float a, float b) {
  u32 r;
  asm("v_cvt_pk_bf16_f32 %0, %1, %2" : "=v"(r) : "v"(a), "v"(b));
  return r;
}

__device__ __forceinline__ void gload16(const u16* g, u16* l) {
  __builtin_amdgcn_global_load_lds(
      (const __attribute__((address_space(1))) u32*)g,
      (__attribute__((address_space(3))) u32*)l, 16, 0, 0);
}

// ---------------- f32 -> bf16 elementwise convert ---------------------------
__global__ __launch_bounds__(256) void k_cvt(const float* __restrict__ src,
                                             u16* __restrict__ dst) {
  int i = (blockIdx.x * 256 + threadIdx.x) * 8;
  float4 v0 = *(const float4*)(src + i);
  float4 v1 = *(const float4*)(src + i + 4);
  ushort4 w0, w1;
  w0.x = f2bf(v0.x); w0.y = f2bf(v0.y); w0.z = f2bf(v0.z); w0.w = f2bf(v0.w);
  w1.x = f2bf(v1.x); w1.y = f2bf(v1.y); w1.z = f2bf(v1.z); w1.w = f2bf(v1.w);
  *(ushort4*)(dst + i) = w0;
  *(ushort4*)(dst + i + 4) = w1;
}

// ------- transpose + convert body: src[K][N] f32 -> dst[N][K] bf16 ----------
__device__ __forceinline__ void transpose_body(const float* __restrict__ src,
                                               u16* __restrict__ dst,
                                               int N, int K, int nt, int kt,
                                               int t) {
  __shared__ float T[64][65];
#pragma unroll
  for (int it = 0; it < 4; ++it) {
    int r = it * 16 + (t >> 4), c = (t & 15) * 4;
    float4 v = *(const float4*)(src + (size_t)(kt + r) * N + nt + c);
    T[r][c] = v.x; T[r][c + 1] = v.y; T[r][c + 2] = v.z; T[r][c + 3] = v.w;
  }
  __syncthreads();
#pragma unroll
  for (int it = 0; it < 2; ++it) {
    int n = it * 32 + (t >> 3), k8 = (t & 7) * 8;
    ushort4 w0, w1;
    w0.x = f2bf(T[k8 + 0][n]); w0.y = f2bf(T[k8 + 1][n]);
    w0.z = f2bf(T[k8 + 2][n]); w0.w = f2bf(T[k8 + 3][n]);
    w1.x = f2bf(T[k8 + 4][n]); w1.y = f2bf(T[k8 + 5][n]);
    w1.z = f2bf(T[k8 + 6][n]); w1.w = f2bf(T[k8 + 7][n]);
    *(ushort4*)(dst + (size_t)(nt + n) * K + kt + k8) = w0;
    *(ushort4*)(dst + (size_t)(nt + n) * K + kt + k8 + 4) = w1;
  }
}

__global__ __launch_bounds__(256) void k_transpose(const float* __restrict__ src,
                                                   u16* __restrict__ dst,
                                                   int N, int K) {
  transpose_body(src, dst, N, K, blockIdx.x * 64, blockIdx.y * 64, threadIdx.x);
}

// merged Wq|Wk|Wv transpose (one launch)
__global__ __launch_bounds__(256) void k_transpose_qkv(const float* __restrict__ Wq,
                                                       const float* __restrict__ Wk,
                                                       const float* __restrict__ Wv,
                                                       u16* __restrict__ WT) {
  const int bx = blockIdx.x;
  const float* src; u16* dst; int N, nt;
  if (bx < 32)      { src = Wq; dst = WT;                    N = 2048; nt = bx * 64; }
  else if (bx < 40) { src = Wk; dst = WT + 2048ull * 2048;   N = 512;  nt = (bx - 32) * 64; }
  else              { src = Wv; dst = WT + 2560ull * 2048;   N = 512;  nt = (bx - 40) * 64; }
  transpose_body(src, dst, N, 2048, nt, blockIdx.y * 64, threadIdx.x);
}

// ------- V transpose: QKV V-section [s][2560+gd] bf16 -> Vt[gd][s] bf16 -----
__global__ __launch_bounds__(256) void k_vt(const u16* __restrict__ QKV,
                                            u16* __restrict__ Vt) {
  __shared__ u16 T[64][66];
  const int t = threadIdx.x;
  const int s0 = blockIdx.x * 64, d0 = blockIdx.y * 64;
#pragma unroll
  for (int it = 0; it < 4; ++it) {
    int r = it * 16 + (t >> 4), c = (t & 15) * 4;
    ushort4 v = *(const ushort4*)(QKV + (size_t)(s0 + r) * QKVP + 2560 + d0 + c);
    T[r][c] = v.x; T[r][c + 1] = v.y; T[r][c + 2] = v.z; T[r][c + 3] = v.w;
  }
  __syncthreads();
#pragma unroll
  for (int it = 0; it < 4; ++it) {
    int dd = it * 16 + (t >> 4), sc = (t & 15) * 4;
    ushort4 w;
    w.x = T[sc + 0][dd]; w.y = T[sc + 1][dd];
    w.z = T[sc + 2][dd]; w.w = T[sc + 3][dd];
    *(ushort4*)(Vt + (size_t)(d0 + dd) * S + s0 + sc) = w;
  }
}

// ---------------- MFMA GEMM: BK=64, 2-phase prefetch, XOR-swizzled LDS ------
// (R5-proven: conflict-free frag reads, 32 MFMAs per barrier)
__global__ __launch_bounds__(256) void k_gemm_mfma(const u16* __restrict__ A,
                                                   const u16* __restrict__ BT,
                                                   void* __restrict__ Cout,
                                                   int N, int K, int out_bf16) {
  __shared__ __align__(16) u16 As[2][128 * 64];
  __shared__ __align__(16) u16 Bs[2][128 * 64];
  const int t = threadIdx.x, w = t >> 6, lane = t & 63;
  const int l15 = lane & 15, quad = lane >> 4;
  const int m0 = blockIdx.y * 128, n0 = blockIdx.x * 128;
  const int wr = w >> 1, wc = w & 1;

  // staging: per issue, wave covers 8 rows (8 lanes/row, 16B each).
  const int srow = lane >> 3;                       // 0..7 within issue
  const int schunk = (lane & 7) ^ srow;             // pre-swizzled source chunk
  const u16* Agb = A + (size_t)(m0 + w * 8 + srow) * K + schunk * 8;
  const u16* Bgb = BT + (size_t)(n0 + w * 8 + srow) * K + schunk * 8;

  f32x4 acc[4][4];
#pragma unroll
  for (int i = 0; i < 4; ++i)
#pragma unroll
    for (int j = 0; j < 4; ++j) acc[i][j] = (f32x4){0.f, 0.f, 0.f, 0.f};

  auto STAGE = [&](int k0, int b) {
#pragma unroll
    for (int it = 0; it < 4; ++it) {
      gload16(Agb + (size_t)it * 32 * K + k0, &As[b][(w * 8 + it * 32) * 64]);
      gload16(Bgb + (size_t)it * 32 * K + k0, &Bs[b][(w * 8 + it * 32) * 64]);
    }
  };

  STAGE(0, 0);
  __syncthreads();  // buf0 ready
  int cur = 0;
  for (int k0 = 0; k0 < K; k0 += 64) {
    if (k0 + 64 < K) STAGE(k0 + 64, cur ^ 1);  // issue next tile early

    short8 af[4][2], bf[4][2];
#pragma unroll
    for (int i = 0; i < 4; ++i)
#pragma unroll
      for (int k2 = 0; k2 < 2; ++k2) {
        int ch = (k2 * 4 + quad) ^ (l15 & 7);
        af[i][k2] = *(const short8*)&As[cur][(wr * 64 + i * 16 + l15) * 64 + ch * 8];
        bf[i][k2] = *(const short8*)&Bs[cur][(wc * 64 + i * 16 + l15) * 64 + ch * 8];
      }
#pragma unroll
    for (int k2 = 0; k2 < 2; ++k2)
#pragma unroll
      for (int i = 0; i < 4; ++i)
#pragma unroll
        for (int j = 0; j < 4; ++j)
          acc[i][j] = __builtin_amdgcn_mfma_f32_16x16x32_bf16(af[i][k2], bf[j][k2], acc[i][j], 0, 0, 0);

    __syncthreads();  // drains prefetch + all waves done reading cur
    cur ^= 1;
  }

  if (out_bf16) {
    u16* C = (u16*)Cout;
#pragma unroll
    for (int i = 0; i < 4; ++i)
#pragma unroll
      for (int j = 0; j < 4; ++j) {
        int col = n0 + wc * 64 + j * 16 + l15;
#pragma unroll
        for (int r = 0; r < 4; ++r)
          C[(size_t)(m0 + wr * 64 + i * 16 + quad * 4 + r) * N + col] = f2bf(acc[i][j][r]);
      }
  } else {
    float* C = (float*)Cout;
#pragma unroll
    for (int i = 0; i < 4; ++i)
#pragma unroll
      for (int j = 0; j < 4; ++j) {
        int col = n0 + wc * 64 + j * 16 + l15;
#pragma unroll
        for (int r = 0; r < 4; ++r)
          C[(size_t)(m0 + wr * 64 + i * 16 + quad * 4 + r) * N + col] = acc[i][j][r];
      }
  }
}

// ------------- per-(s,head) RMSNorm + RoPE, Q and K in one launch (R1) ------
__global__ __launch_bounds__(128) void k_norm_rope(u16* __restrict__ QKV,
                                                   const float* __restrict__ qsc,
                                                   const float* __restrict__ ksc,
                                                   const float* __restrict__ cosp,
                                                   const float* __restrict__ sinp) {
  const int s = blockIdx.x, hh = blockIdx.y, d = threadIdx.x;
  u16* row; const float* sc; float scale;
  if (hh < NH) { row = QKV + (size_t)s * QKVP + hh * D;            sc = qsc; scale = QSCALE; }
  else         { row = QKV + (size_t)s * QKVP + 2048 + (hh - NH) * D; sc = ksc; scale = 1.0f; }
  float x = bf2f(row[d]);
  float v = x * x;
#pragma unroll
  for (int o = 32; o; o >>= 1) v += __shfl_xor(v, o, 64);
  __shared__ float red[2];
  if ((d & 63) == 0) red[d >> 6] = v;
  __syncthreads();
  float var = (red[0] + red[1]) * (1.0f / 128.0f);
  float rinv = rsqrtf(var + 1e-6f) * scale;
  float xn = x * rinv * sc[d];
  __shared__ float sh[D];
  sh[d] = xn;
  __syncthreads();
  float rot = (d < 64) ? -sh[d + 64] : sh[d - 64];
  row[d] = f2bf(xn * cosp[s * D + d] + rot * sinp[s * D + d]);
}

// ---------------- flash attention v6: fully register-resident, zero-barrier -
// Block: 256 thr (4 waves) = 64-row q-tile of one head; 64-key tiles.
// K AND V fragments load DIRECTLY from global (both L2-resident: 512KB K
// slice + 2MB Vt per group) into MFMA-layout registers -- the exact elements
// the old DMA staged, same lane mapping. No K LDS, no global_load_lds, no
// s_waitcnt asm, ZERO __syncthreads (Pt is wave-private). Per-tile chain is
// pure {independent loads -> MFMA -> softmax -> MFMA}; compiler schedules,
// 2 waves/SIMD overlap the rest.
// Softmax: exp2-domain + hardened defer-rescale (THR=8, jt==0 forces alpha=0).
#define PTP 72   // P pitch (u16): b64-write / b128-read aligned

__global__ __launch_bounds__(256) void k_flash(const u16* __restrict__ QKV,
                                               const u16* __restrict__ Vt,
                                               u16* __restrict__ O) {
  const int h = blockIdx.y, g = h >> 2;
  const int qt = (h < 8) ? (31 - (int)blockIdx.x) : (int)blockIdx.x;
  const int t = threadIdx.x;
  const int w = t >> 6, lane = t & 63, l15 = lane & 15, quad = lane >> 4;

  __shared__ __align__(16) u16 Pt[4][16 * PTP];    // per-wave P staging

  const int qrow = qt * 64 + w * 16 + l15;

  short8 qf[4];
  {
    const u16* qp = QKV + (size_t)qrow * QKVP + h * D + quad * 8;
#pragma unroll
    for (int c = 0; c < 4; ++c) qf[c] = *(const short8*)(qp + c * 32);
  }

  float m = NEG_INF, l = 0.f;
  f32x4 oacc[8];
#pragma unroll
  for (int nc = 0; nc < 8; ++nc) oacc[nc] = (f32x4){0.f, 0.f, 0.f, 0.f};

  const int nt = qt + 1;
  const u16* Kb = QKV + 2048 + (size_t)g * D;      // K row base (row stride QKVP)
  const u16* Vb = Vt + (size_t)g * D * S;          // V^T base  (row stride S)

  for (int jt = 0; jt < nt; ++jt) {
    const int j0 = jt * 64;

    // V fragments kc=0 (keys j0+quad*8..+7): issue first, consumed last ->
    // L2 latency hides under QK^T + softmax.
    short8 vf0[8];
#pragma unroll
    for (int nc = 0; nc < 8; ++nc)
      vf0[nc] = *(const short8*)(Vb + (size_t)(nc * 16 + l15) * S + j0 + quad * 8);

    // ---- S^T = K x Q^T : row = key (quad*4+r +16sub), col = q-row (l15) ----
    // kf direct from global: K[j0+sub*16+l15][(c*4+quad)*8..] -- identical
    // elements/lanes as the old LDS-staged path.
    f32x4 sa[4];
#pragma unroll
    for (int sub = 0; sub < 4; ++sub) {
      const u16* krow = Kb + (size_t)(j0 + sub * 16 + l15) * QKVP + quad * 8;
      f32x4 acc = {0.f, 0.f, 0.f, 0.f};
#pragma unroll
      for (int c = 0; c < 4; ++c) {
        short8 kf = *(const short8*)(krow + c * 32);
        acc = __builtin_amdgcn_mfma_f32_16x16x32_bf16(kf, qf[c], acc, 0, 0, 0);
      }
      sa[sub] = acc;
    }

    // V fragments kc=1 (keys j0+32+quad*8..+7)
    short8 vf1[8];
#pragma unroll
    for (int nc = 0; nc < 8; ++nc)
      vf1[nc] = *(const short8*)(Vb + (size_t)(nc * 16 + l15) * S + j0 + 32 + quad * 8);

    if (jt == nt - 1) {  // causal mask, diagonal tile only
#pragma unroll
      for (int sub = 0; sub < 4; ++sub) {
        int keyb = j0 + sub * 16 + quad * 4;
#pragma unroll
        for (int r = 0; r < 4; ++r)
          if (keyb + r > qrow) sa[sub][r] = NEG_INF;
      }
    }

    // ---- online softmax (exp2 domain, hardened defer-rescale THR=8) -------
    float tmax = sa[0][0];
#pragma unroll
    for (int sub = 0; sub < 4; ++sub)
#pragma unroll
      for (int r = 0; r < 4; ++r) tmax = fmaxf(tmax, sa[sub][r]);
    tmax = fmaxf(tmax, __shfl_xor(tmax, 16, 64));
    tmax = fmaxf(tmax, __shfl_xor(tmax, 32, 64));
    if (jt == 0 || !__all(tmax - m <= 8.f)) {
      float mn = (jt == 0) ? tmax : fmaxf(m, tmax);
      float alpha = (jt == 0) ? 0.f : exp2_hw(m - mn);
      m = mn;
      l *= alpha;
#pragma unroll
      for (int nc = 0; nc < 8; ++nc) {
        oacc[nc][0] *= alpha; oacc[nc][1] *= alpha;
        oacc[nc][2] *= alpha; oacc[nc][3] *= alpha;
      }
    }
    float rs = 0.f;
#pragma unroll
    for (int sub = 0; sub < 4; ++sub) {
      float p0 = exp2_hw(sa[sub][0] - m);
      float p1 = exp2_hw(sa[sub][1] - m);
      float p2 = exp2_hw(sa[sub][2] - m);
      float p3 = exp2_hw(sa[sub][3] - m);
      rs += (p0 + p1) + (p2 + p3);
      u32 lo = cvt_pk_bf16(p0, p1);
      u32 hi = cvt_pk_bf16(p2, p3);
      *(uint2*)&Pt[w][l15 * PTP + sub * 16 + quad * 4] = make_uint2(lo, hi);
    }
    rs += __shfl_xor(rs, 16, 64);
    rs += __shfl_xor(rs, 32, 64);
    l += rs;

    // ---- O^T += V^T x P^T (all operands in regs) --------------------------
    {
      short8 pf0 = *(const short8*)&Pt[w][l15 * PTP + quad * 8];
      short8 pf1 = *(const short8*)&Pt[w][l15 * PTP + 32 + quad * 8];
#pragma unroll
      for (int nc = 0; nc < 8; ++nc)
        oacc[nc] = __builtin_amdgcn_mfma_f32_16x16x32_bf16(vf0[nc], pf0, oacc[nc], 0, 0, 0);
#pragma unroll
      for (int nc = 0; nc < 8; ++nc)
        oacc[nc] = __builtin_amdgcn_mfma_f32_16x16x32_bf16(vf1[nc], pf1, oacc[nc], 0, 0, 0);
    }
  }

  // ---- epilogue: O[q][d] = O^T / l ----
  float inv = 1.0f / l;
  u16* orow = O + (size_t)qrow * HID + h * D;
#pragma unroll
  for (int nc = 0; nc < 8; ++nc) {
    ushort4 wv;
    wv.x = f2bf(oacc[nc][0] * inv); wv.y = f2bf(oacc[nc][1] * inv);
    wv.z = f2bf(oacc[nc][2] * inv); wv.w = f2bf(oacc[nc][3] * inv);
    *(ushort4*)(orow + nc * 16 + quad * 4) = wv;
  }
}

// ---------------- final RMSNorm over HIDDEN=2048 ----------------------------
__device__ __forceinline__ float blockSum256(float v, float* red, int t) {
#pragma unroll
  for (int o = 32; o; o >>= 1) v += __shfl_xor(v, o, 64);
  if ((t & 63) == 0) red[t >> 6] = v;
  __syncthreads();
  v = red[0] + red[1] + red[2] + red[3];
  __syncthreads();
  return v;
}

__global__ __launch_bounds__(256) void k_fnorm(const float* __restrict__ X,
                                               const float* __restrict__ sc,
                                               float* __restrict__ out) {
  const int s = blockIdx.x, t = threadIdx.x;
  const float* row = X + (size_t)s * HID;
  float4 r0 = *(const float4*)(row + t * 8);
  float4 r1 = *(const float4*)(row + t * 8 + 4);
  float x[8] = {r0.x, r0.y, r0.z, r0.w, r1.x, r1.y, r1.z, r1.w};
  float ss = 0.f;
#pragma unroll
  for (int ii = 0; ii < 8; ++ii) ss += x[ii] * x[ii];
  __shared__ float red[4];
  float tot = blockSum256(ss, red, t);
  float rinv = rsqrtf(tot * (1.0f / 2048.0f) + 1e-6f);
  float4 s0 = *(const float4*)(sc + t * 8);
  float4 s1 = *(const float4*)(sc + t * 8 + 4);
  float4 w0 = make_float4(x[0] * rinv * s0.x, x[1] * rinv * s0.y,
                          x[2] * rinv * s0.z, x[3] * rinv * s0.w);
  float4 w1 = make_float4(x[4] * rinv * s1.x, x[5] * rinv * s1.y,
                          x[6] * rinv * s1.z, x[7] * rinv * s1.w);
  *(float4*)(out + (size_t)s * HID + t * 8) = w0;
  *(float4*)(out + (size_t)s * HID + t * 8 + 4) = w1;
}

extern "C" void kernel_launch(void* const* d_in, const int* in_sizes, int n_in,
                              void* d_out, int out_size, void* d_ws, size_t ws_size,
                              hipStream_t stream) {
  const float* hidden = (const float*)d_in[0];
  const float* cosp   = (const float*)d_in[1];
  const float* sinp   = (const float*)d_in[2];
  const float* Wq     = (const float*)d_in[3];
  const float* Wk     = (const float*)d_in[4];
  const float* Wv     = (const float*)d_in[5];
  const float* Wo     = (const float*)d_in[6];
  const float* qsc    = (const float*)d_in[7];
  const float* ksc    = (const float*)d_in[8];
  const float* lsc    = (const float*)d_in[9];
  float* out = (float*)d_out;

  char* ws = (char*)d_ws;
  u16*   Hb  = (u16*)(ws);                   // [S][HID] bf16, 8 MiB
  u16*   WoT = (u16*)(ws);                   // overlays Hb (after QKV GEMM)
  u16*   WT  = (u16*)(ws + (8ull << 20));    // [3072][2048] bf16, 12 MiB
  u16*   An  = (u16*)(ws + (8ull << 20));    // overlays WT (after QKV GEMM)
  u16*   QKV = (u16*)(ws + (20ull << 20));   // [S][3072] bf16, 12 MiB
  float* Ob  = (float*)(ws + (20ull << 20)); // overlays QKV (after flash)
  u16*   Vtb = (u16*)(ws + (32ull << 20));   // [512][2048] bf16, 2 MiB

  k_cvt<<<S * HID / (256 * 8), 256, 0, stream>>>(hidden, Hb);
  k_transpose_qkv<<<dim3(48, 32), 256, 0, stream>>>(Wq, Wk, Wv, WT);
  k_gemm_mfma<<<dim3(24, 16), 256, 0, stream>>>(Hb, WT, QKV, QKVP, 2048, 1);
  k_transpose<<<dim3(32, 32), 256, 0, stream>>>(Wo, WoT, 2048, 2048);  // Hb dead
  k_norm_rope<<<dim3(S, NH + NKV), 128, 0, stream>>>(QKV, qsc, ksc, cosp, sinp);
  k_vt<<<dim3(32, 8), 256, 0, stream>>>(QKV, Vtb);
  k_flash<<<dim3(32, NH), 256, 0, stream>>>(QKV, Vtb, An);
  k_gemm_mfma<<<dim3(16, 16), 256, 0, stream>>>(An, WoT, Ob, 2048, 2048, 0);
  k_fnorm<<<S, 256, 0, stream>>>(Ob, lsc, out);
}

// Round 7
// 306.762 us; speedup vs baseline: 1.0898x; 1.0898x over previous
//
#include <hip/hip_runtime.h>

typedef unsigned short u16;
typedef unsigned int u32;

#define S 2048
#define HID 2048
#define NH 16
#define NKV 4
#define D 128
#define QKVP 3072  // QKV buffer pitch (Q|K|V concat per row)
// 1/sqrt(128) * log2(e): scores come out of QK^T already in log2 domain
#define QSCALE (0.08838834764831845f * 1.4426950408889634f)
#define NEG_INF -3.0e38f

typedef __attribute__((ext_vector_type(8))) short short8;  // 8 bf16 = 4 VGPRs
typedef __attribute__((ext_vector_type(4))) float f32x4;

__device__ __forceinline__ float bf2f(u16 u) {
  union { u32 i; float f; } c; c.i = ((u32)u) << 16; return c.f;
}
__device__ __forceinline__ u16 f2bf(float f) {
  union { float f; u32 i; } c; c.f = f;
  u32 x = c.i;
  u32 r = x + 0x7fffu + ((x >> 16) & 1u);  // RNE
  return (u16)(r >> 16);
}

#if __has_builtin(__builtin_amdgcn_exp2f)
__device__ __forceinline__ float exp2_hw(float x) { return __builtin_amdgcn_exp2f(x); }
#else
__device__ __forceinline__ float exp2_hw(float x) { return exp2f(x); }
#endif

// packed f32x2 -> bf16x2 (RNE), single VOP3
__device__ __forceinline__ u32 cvt_pk_bf16(float a, float b) {
  u32 r;
  asm("v_cvt_pk_bf16_f32 %0, %1, %2" : "=v"(r) : "v"(a), "v"(b));
  return r;
}

__device__ __forceinline__ void gload16(const u16* g, u16* l) {
  __builtin_amdgcn_global_load_lds(
      (const __attribute__((address_space(1))) u32*)g,
      (__attribute__((address_space(3))) u32*)l, 16, 0, 0);
}

// ---------------- f32 -> bf16 elementwise convert ---------------------------
__global__ __launch_bounds__(256) void k_cvt(const float* __restrict__ src,
                                             u16* __restrict__ dst) {
  int i = (blockIdx.x * 256 + threadIdx.x) * 8;
  float4 v0 = *(const float4*)(src + i);
  float4 v1 = *(const float4*)(src + i + 4);
  ushort4 w0, w1;
  w0.x = f2bf(v0.x); w0.y = f2bf(v0.y); w0.z = f2bf(v0.z); w0.w = f2bf(v0.w);
  w1.x = f2bf(v1.x); w1.y = f2bf(v1.y); w1.z = f2bf(v1.z); w1.w = f2bf(v1.w);
  *(ushort4*)(dst + i) = w0;
  *(ushort4*)(dst + i + 4) = w1;
}

// ------- transpose + convert body: src[K][N] f32 -> dst[N][K] bf16 ----------
__device__ __forceinline__ void transpose_body(const float* __restrict__ src,
                                               u16* __restrict__ dst,
                                               int N, int K, int nt, int kt,
                                               int t) {
  __shared__ float T[64][65];
#pragma unroll
  for (int it = 0; it < 4; ++it) {
    int r = it * 16 + (t >> 4), c = (t & 15) * 4;
    float4 v = *(const float4*)(src + (size_t)(kt + r) * N + nt + c);
    T[r][c] = v.x; T[r][c + 1] = v.y; T[r][c + 2] = v.z; T[r][c + 3] = v.w;
  }
  __syncthreads();
#pragma unroll
  for (int it = 0; it < 2; ++it) {
    int n = it * 32 + (t >> 3), k8 = (t & 7) * 8;
    ushort4 w0, w1;
    w0.x = f2bf(T[k8 + 0][n]); w0.y = f2bf(T[k8 + 1][n]);
    w0.z = f2bf(T[k8 + 2][n]); w0.w = f2bf(T[k8 + 3][n]);
    w1.x = f2bf(T[k8 + 4][n]); w1.y = f2bf(T[k8 + 5][n]);
    w1.z = f2bf(T[k8 + 6][n]); w1.w = f2bf(T[k8 + 7][n]);
    *(ushort4*)(dst + (size_t)(nt + n) * K + kt + k8) = w0;
    *(ushort4*)(dst + (size_t)(nt + n) * K + kt + k8 + 4) = w1;
  }
}

__global__ __launch_bounds__(256) void k_transpose(const float* __restrict__ src,
                                                   u16* __restrict__ dst,
                                                   int N, int K) {
  transpose_body(src, dst, N, K, blockIdx.x * 64, blockIdx.y * 64, threadIdx.x);
}

// merged Wq|Wk|Wv transpose (one launch)
__global__ __launch_bounds__(256) void k_transpose_qkv(const float* __restrict__ Wq,
                                                       const float* __restrict__ Wk,
                                                       const float* __restrict__ Wv,
                                                       u16* __restrict__ WT) {
  const int bx = blockIdx.x;
  const float* src; u16* dst; int N, nt;
  if (bx < 32)      { src = Wq; dst = WT;                    N = 2048; nt = bx * 64; }
  else if (bx < 40) { src = Wk; dst = WT + 2048ull * 2048;   N = 512;  nt = (bx - 32) * 64; }
  else              { src = Wv; dst = WT + 2560ull * 2048;   N = 512;  nt = (bx - 40) * 64; }
  transpose_body(src, dst, N, 2048, nt, blockIdx.y * 64, threadIdx.x);
}

// ------- V transpose: QKV V-section [s][2560+gd] bf16 -> Vt[gd][s] bf16 -----
__global__ __launch_bounds__(256) void k_vt(const u16* __restrict__ QKV,
                                            u16* __restrict__ Vt) {
  __shared__ u16 T[64][66];
  const int t = threadIdx.x;
  const int s0 = blockIdx.x * 64, d0 = blockIdx.y * 64;
#pragma unroll
  for (int it = 0; it < 4; ++it) {
    int r = it * 16 + (t >> 4), c = (t & 15) * 4;
    ushort4 v = *(const ushort4*)(QKV + (size_t)(s0 + r) * QKVP + 2560 + d0 + c);
    T[r][c] = v.x; T[r][c + 1] = v.y; T[r][c + 2] = v.z; T[r][c + 3] = v.w;
  }
  __syncthreads();
#pragma unroll
  for (int it = 0; it < 4; ++it) {
    int dd = it * 16 + (t >> 4), sc = (t & 15) * 4;
    ushort4 w;
    w.x = T[sc + 0][dd]; w.y = T[sc + 1][dd];
    w.z = T[sc + 2][dd]; w.w = T[sc + 3][dd];
    *(ushort4*)(Vt + (size_t)(d0 + dd) * S + s0 + sc) = w;
  }
}

// ------- MFMA GEMM: BM=128 x BN=64, BK=64, 2-phase prefetch, XOR swizzle ----
// R5's proven BK=64 swizzled staging/reads, at BN=64 so grids are exact
// multiples of 256 CUs: QKV 768 blocks = 3.0/CU (was 1.5 -> 25% imbalance),
// Wo 512 = 2.0/CU (was 1.0, zero TLP). LDS 48KB -> 3 blocks/CU.
// Wave w owns a 32x64 output tile: acc[2][4].
__global__ __launch_bounds__(256) void k_gemm_mfma(const u16* __restrict__ A,
                                                   const u16* __restrict__ BT,
                                                   void* __restrict__ Cout,
                                                   int N, int K, int out_bf16) {
  __shared__ __align__(16) u16 As[2][128 * 64];
  __shared__ __align__(16) u16 Bs[2][64 * 64];
  const int t = threadIdx.x, w = t >> 6, lane = t & 63;
  const int l15 = lane & 15, quad = lane >> 4;
  const int m0 = blockIdx.y * 128, n0 = blockIdx.x * 64;

  // staging: per issue, wave covers 8 rows (8 lanes/row, 16B each).
  const int srow = lane >> 3;                       // 0..7 within issue
  const int schunk = (lane & 7) ^ srow;             // pre-swizzled source chunk
  const u16* Agb = A + (size_t)(m0 + w * 8 + srow) * K + schunk * 8;
  const u16* Bgb = BT + (size_t)(n0 + w * 8 + srow) * K + schunk * 8;

  f32x4 acc[2][4];
#pragma unroll
  for (int i = 0; i < 2; ++i)
#pragma unroll
    for (int j = 0; j < 4; ++j) acc[i][j] = (f32x4){0.f, 0.f, 0.f, 0.f};

  auto STAGE = [&](int k0, int b) {
#pragma unroll
    for (int it = 0; it < 4; ++it)
      gload16(Agb + (size_t)it * 32 * K + k0, &As[b][(w * 8 + it * 32) * 64]);
#pragma unroll
    for (int it = 0; it < 2; ++it)
      gload16(Bgb + (size_t)it * 32 * K + k0, &Bs[b][(w * 8 + it * 32) * 64]);
  };

  STAGE(0, 0);
  __syncthreads();  // buf0 ready
  int cur = 0;
  for (int k0 = 0; k0 < K; k0 += 64) {
    if (k0 + 64 < K) STAGE(k0 + 64, cur ^ 1);  // issue next tile early

    short8 af[2][2], bf[4][2];
#pragma unroll
    for (int k2 = 0; k2 < 2; ++k2) {
      int ch = (k2 * 4 + quad) ^ (l15 & 7);
#pragma unroll
      for (int i = 0; i < 2; ++i)
        af[i][k2] = *(const short8*)&As[cur][(w * 32 + i * 16 + l15) * 64 + ch * 8];
#pragma unroll
      for (int j = 0; j < 4; ++j)
        bf[j][k2] = *(const short8*)&Bs[cur][(j * 16 + l15) * 64 + ch * 8];
    }
#pragma unroll
    for (int k2 = 0; k2 < 2; ++k2)
#pragma unroll
      for (int i = 0; i < 2; ++i)
#pragma unroll
        for (int j = 0; j < 4; ++j)
          acc[i][j] = __builtin_amdgcn_mfma_f32_16x16x32_bf16(af[i][k2], bf[j][k2], acc[i][j], 0, 0, 0);

    __syncthreads();  // drains prefetch + all waves done reading cur
    cur ^= 1;
  }

  if (out_bf16) {
    u16* C = (u16*)Cout;
#pragma unroll
    for (int i = 0; i < 2; ++i)
#pragma unroll
      for (int j = 0; j < 4; ++j) {
        int col = n0 + j * 16 + l15;
#pragma unroll
        for (int r = 0; r < 4; ++r)
          C[(size_t)(m0 + w * 32 + i * 16 + quad * 4 + r) * N + col] = f2bf(acc[i][j][r]);
      }
  } else {
    float* C = (float*)Cout;
#pragma unroll
    for (int i = 0; i < 2; ++i)
#pragma unroll
      for (int j = 0; j < 4; ++j) {
        int col = n0 + j * 16 + l15;
#pragma unroll
        for (int r = 0; r < 4; ++r)
          C[(size_t)(m0 + w * 32 + i * 16 + quad * 4 + r) * N + col] = acc[i][j][r];
      }
  }
}

// ------------- per-(s,head) RMSNorm + RoPE, Q and K in one launch (R1) ------
__global__ __launch_bounds__(128) void k_norm_rope(u16* __restrict__ QKV,
                                                   const float* __restrict__ qsc,
                                                   const float* __restrict__ ksc,
                                                   const float* __restrict__ cosp,
                                                   const float* __restrict__ sinp) {
  const int s = blockIdx.x, hh = blockIdx.y, d = threadIdx.x;
  u16* row; const float* sc; float scale;
  if (hh < NH) { row = QKV + (size_t)s * QKVP + hh * D;            sc = qsc; scale = QSCALE; }
  else         { row = QKV + (size_t)s * QKVP + 2048 + (hh - NH) * D; sc = ksc; scale = 1.0f; }
  float x = bf2f(row[d]);
  float v = x * x;
#pragma unroll
  for (int o = 32; o; o >>= 1) v += __shfl_xor(v, o, 64);
  __shared__ float red[2];
  if ((d & 63) == 0) red[d >> 6] = v;
  __syncthreads();
  float var = (red[0] + red[1]) * (1.0f / 128.0f);
  float rinv = rsqrtf(var + 1e-6f) * scale;
  float xn = x * rinv * sc[d];
  __shared__ float sh[D];
  sh[d] = xn;
  __syncthreads();
  float rot = (d < 64) ? -sh[d + 64] : sh[d - 64];
  row[d] = f2bf(xn * cosp[s * D + d] + rot * sinp[s * D + d]);
}

// ---------------- flash attention (R1-proven, 91.5us): pipelined K-DMA ------
// Block: 256 thr (4 waves) = 64-row q-tile of one head.
// K: global_load_lds into double-buffered unpadded LDS, SOURCE-chunk-swizzled
//    (chunk ^= row&7) so frag reads are conflict-free; DMA for tile jt+1
//    issues during compute of jt -> latency hidden behind compute.
// V: register-prefetched (ping-pong), written XOR-swizzled.
// P: packed bf16 pairs -> 4 ds_write_b64 + 2 ds_read_b128 per tile/wave.
#define KP 128   // K LDS row pitch (u16), unpadded (DMA requirement)
#define PTP 72   // P pitch (u16): b64-write / b128-read aligned

__global__ __launch_bounds__(256) void k_flash(const u16* __restrict__ QKV,
                                               const u16* __restrict__ Vt,
                                               u16* __restrict__ O) {
  const int h = blockIdx.y, g = h >> 2;
  const int qt = (h < 8) ? (31 - (int)blockIdx.x) : (int)blockIdx.x;
  const int t = threadIdx.x;
  const int w = t >> 6, lane = t & 63, l15 = lane & 15, quad = lane >> 4;

  __shared__ __align__(16) u16 Klds[2][64 * KP];
  __shared__ __align__(16) u16 Vlds[128 * 64];     // [d][key], XOR-swizzled
  __shared__ __align__(16) u16 Pt[4][16 * PTP];    // [qcol][key] per wave

  const int qbase = qt * 64 + w * 16;
  const int qrow = qbase + l15;

  short8 qf[4];
  {
    const u16* qp = QKV + (size_t)qrow * QKVP + h * D + quad * 8;
#pragma unroll
    for (int c = 0; c < 4; ++c) qf[c] = *(const short8*)(qp + c * 32);
  }

  float m = NEG_INF, l = 0.f;
  f32x4 oacc[8];
#pragma unroll
  for (int nc = 0; nc < 8; ++nc) oacc[nc] = (f32x4){0.f, 0.f, 0.f, 0.f};

  const int nt = qt + 1;
  const int dd = t >> 3, cc = t & 7;  // V staging coords

  auto KLOAD = [&](int j0, int b) {  // DMA 4 rows per wave per issue
#pragma unroll
    for (int it = 0; it < 4; ++it) {
      int rl = w * 16 + it * 4 + quad;                 // tile-local key row
      int gchunk = (lane & 15) ^ (rl & 7);             // source swizzle
      const u16* gp = QKV + (size_t)(j0 + rl) * QKVP + 2048 + g * D + gchunk * 8;
      gload16(gp, &Klds[b][(w * 16 + it * 4) * KP]);
    }
  };
  auto VLOAD = [&](int j0, uint4* vr) {
#pragma unroll
    for (int it = 0; it < 4; ++it)
      vr[it] = *(const uint4*)(Vt + (size_t)(g * D + dd + it * 32) * S + j0 + cc * 8);
  };
  auto VWRITE = [&](uint4* vr) {
#pragma unroll
    for (int it = 0; it < 4; ++it) {
      int d = dd + it * 32;
      *(uint4*)&Vlds[d * 64 + ((cc ^ (d & 7)) * 8)] = vr[it];
    }
  };
  auto COMPUTE = [&](int jt, int b) {
    const int j0 = jt * 64;
    // ---- S^T = K x Q^T : row = key (quad*4+r +16sub), col = q-row (l15) ----
    f32x4 sa[4];
#pragma unroll
    for (int sub = 0; sub < 4; ++sub) {
      f32x4 acc = {0.f, 0.f, 0.f, 0.f};
#pragma unroll
      for (int c = 0; c < 4; ++c) {
        int ch = (c * 4 + quad) ^ (l15 & 7);  // undo source swizzle
        short8 kf = *(const short8*)&Klds[b][(sub * 16 + l15) * KP + ch * 8];
        acc = __builtin_amdgcn_mfma_f32_16x16x32_bf16(kf, qf[c], acc, 0, 0, 0);
      }
      sa[sub] = acc;
    }
    if (jt == nt - 1) {  // causal mask, diagonal tile only
#pragma unroll
      for (int sub = 0; sub < 4; ++sub) {
        int keyb = j0 + sub * 16 + quad * 4;
#pragma unroll
        for (int r = 0; r < 4; ++r)
          if (keyb + r > qrow) sa[sub][r] = NEG_INF;
      }
    }
    // ---- online softmax in exp2 domain (scores pre-scaled by log2e) -------
    float tmax = sa[0][0];
#pragma unroll
    for (int sub = 0; sub < 4; ++sub)
#pragma unroll
      for (int r = 0; r < 4; ++r) tmax = fmaxf(tmax, sa[sub][r]);
    tmax = fmaxf(tmax, __shfl_xor(tmax, 16, 64));
    tmax = fmaxf(tmax, __shfl_xor(tmax, 32, 64));
    float mn = fmaxf(m, tmax);
    float alpha = exp2_hw(m - mn);
    m = mn;
    float rs = 0.f;
#pragma unroll
    for (int sub = 0; sub < 4; ++sub) {
      float p0 = exp2_hw(sa[sub][0] - m);
      float p1 = exp2_hw(sa[sub][1] - m);
      float p2 = exp2_hw(sa[sub][2] - m);
      float p3 = exp2_hw(sa[sub][3] - m);
      rs += (p0 + p1) + (p2 + p3);
      u32 lo = cvt_pk_bf16(p0, p1);
      u32 hi = cvt_pk_bf16(p2, p3);
      *(uint2*)&Pt[w][l15 * PTP + sub * 16 + quad * 4] = make_uint2(lo, hi);
    }
    rs += __shfl_xor(rs, 16, 64);
    rs += __shfl_xor(rs, 32, 64);
    l = l * alpha + rs;
#pragma unroll
    for (int nc = 0; nc < 8; ++nc) {
      oacc[nc][0] *= alpha; oacc[nc][1] *= alpha;
      oacc[nc][2] *= alpha; oacc[nc][3] *= alpha;
    }
    // ---- O^T += V^T x P^T ----
#pragma unroll
    for (int kc = 0; kc < 2; ++kc) {
      short8 pf = *(const short8*)&Pt[w][l15 * PTP + kc * 32 + quad * 8];
#pragma unroll
      for (int nc = 0; nc < 8; ++nc) {
        int d = nc * 16 + l15;
        short8 vf = *(const short8*)&Vlds[d * 64 + (((kc * 4 + quad) ^ (d & 7)) * 8)];
        oacc[nc] = __builtin_amdgcn_mfma_f32_16x16x32_bf16(vf, pf, oacc[nc], 0, 0, 0);
      }
    }
  };

  uint4 vrA[4], vrB[4];
  KLOAD(0, 0);
  VLOAD(0, vrA);
  for (int jt = 0; jt < nt; jt += 2) {
    __syncthreads();                       // prev compute done; K(jt) DMA drained
    VWRITE(vrA);
    __syncthreads();                       // V(jt) visible
    if (jt + 1 < nt) { KLOAD((jt + 1) * 64, 1); VLOAD((jt + 1) * 64, vrB); }
    COMPUTE(jt, 0);
    if (jt + 1 < nt) {
      __syncthreads();
      VWRITE(vrB);
      __syncthreads();
      if (jt + 2 < nt) { KLOAD((jt + 2) * 64, 0); VLOAD((jt + 2) * 64, vrA); }
      COMPUTE(jt + 1, 1);
    }
  }

  // ---- epilogue: O[q][d] = O^T / l ----
  float inv = 1.0f / l;
  u16* orow = O + (size_t)qrow * HID + h * D;
#pragma unroll
  for (int nc = 0; nc < 8; ++nc) {
    ushort4 wv;
    wv.x = f2bf(oacc[nc][0] * inv); wv.y = f2bf(oacc[nc][1] * inv);
    wv.z = f2bf(oacc[nc][2] * inv); wv.w = f2bf(oacc[nc][3] * inv);
    *(ushort4*)(orow + nc * 16 + quad * 4) = wv;
  }
}

// ---------------- final RMSNorm over HIDDEN=2048 ----------------------------
__device__ __forceinline__ float blockSum256(float v, float* red, int t) {
#pragma unroll
  for (int o = 32; o; o >>= 1) v += __shfl_xor(v, o, 64);
  if ((t & 63) == 0) red[t >> 6] = v;
  __syncthreads();
  v = red[0] + red[1] + red[2] + red[3];
  __syncthreads();
  return v;
}

__global__ __launch_bounds__(256) void k_fnorm(const float* __restrict__ X,
                                               const float* __restrict__ sc,
                                               float* __restrict__ out) {
  const int s = blockIdx.x, t = threadIdx.x;
  const float* row = X + (size_t)s * HID;
  float4 r0 = *(const float4*)(row + t * 8);
  float4 r1 = *(const float4*)(row + t * 8 + 4);
  float x[8] = {r0.x, r0.y, r0.z, r0.w, r1.x, r1.y, r1.z, r1.w};
  float ss = 0.f;
#pragma unroll
  for (int ii = 0; ii < 8; ++ii) ss += x[ii] * x[ii];
  __shared__ float red[4];
  float tot = blockSum256(ss, red, t);
  float rinv = rsqrtf(tot * (1.0f / 2048.0f) + 1e-6f);
  float4 s0 = *(const float4*)(sc + t * 8);
  float4 s1 = *(const float4*)(sc + t * 8 + 4);
  float4 w0 = make_float4(x[0] * rinv * s0.x, x[1] * rinv * s0.y,
                          x[2] * rinv * s0.z, x[3] * rinv * s0.w);
  float4 w1 = make_float4(x[4] * rinv * s1.x, x[5] * rinv * s1.y,
                          x[6] * rinv * s1.z, x[7] * rinv * s1.w);
  *(float4*)(out + (size_t)s * HID + t * 8) = w0;
  *(float4*)(out + (size_t)s * HID + t * 8 + 4) = w1;
}

extern "C" void kernel_launch(void* const* d_in, const int* in_sizes, int n_in,
                              void* d_out, int out_size, void* d_ws, size_t ws_size,
                              hipStream_t stream) {
  const float* hidden = (const float*)d_in[0];
  const float* cosp   = (const float*)d_in[1];
  const float* sinp   = (const float*)d_in[2];
  const float* Wq     = (const float*)d_in[3];
  const float* Wk     = (const float*)d_in[4];
  const float* Wv     = (const float*)d_in[5];
  const float* Wo     = (const float*)d_in[6];
  const float* qsc    = (const float*)d_in[7];
  const float* ksc    = (const float*)d_in[8];
  const float* lsc    = (const float*)d_in[9];
  float* out = (float*)d_out;

  char* ws = (char*)d_ws;
  u16*   Hb  = (u16*)(ws);                   // [S][HID] bf16, 8 MiB
  u16*   WoT = (u16*)(ws);                   // overlays Hb (after QKV GEMM)
  u16*   WT  = (u16*)(ws + (8ull << 20));    // [3072][2048] bf16, 12 MiB
  u16*   An  = (u16*)(ws + (8ull << 20));    // overlays WT (after QKV GEMM)
  u16*   QKV = (u16*)(ws + (20ull << 20));   // [S][3072] bf16, 12 MiB
  float* Ob  = (float*)(ws + (20ull << 20)); // overlays QKV (after flash)
  u16*   Vtb = (u16*)(ws + (32ull << 20));   // [512][2048] bf16, 2 MiB

  k_cvt<<<S * HID / (256 * 8), 256, 0, stream>>>(hidden, Hb);
  k_transpose_qkv<<<dim3(48, 32), 256, 0, stream>>>(Wq, Wk, Wv, WT);
  k_gemm_mfma<<<dim3(48, 16), 256, 0, stream>>>(Hb, WT, QKV, QKVP, 2048, 1);
  k_transpose<<<dim3(32, 32), 256, 0, stream>>>(Wo, WoT, 2048, 2048);  // Hb dead
  k_norm_rope<<<dim3(S, NH + NKV), 128, 0, stream>>>(QKV, qsc, ksc, cosp, sinp);
  k_vt<<<dim3(32, 8), 256, 0, stream>>>(QKV, Vtb);
  k_flash<<<dim3(32, NH), 256, 0, stream>>>(QKV, Vtb, An);
  k_gemm_mfma<<<dim3(32, 16), 256, 0, stream>>>(An, WoT, Ob, 2048, 2048, 0);
  k_fnorm<<<S, 256, 0, stream>>>(Ob, lsc, out);
}

// Round 9
// 295.869 us; speedup vs baseline: 1.1299x; 1.0368x over previous
//
#include <hip/hip_runtime.h>

typedef unsigned short u16;
typedef unsigned int u32;

#define S 2048
#define HID 2048
#define NH 16
#define NKV 4
#define D 128
#define QKVP 3072  // QKV buffer pitch (Q|K|V concat per row)
// 1/sqrt(128) * log2(e): scores come out of QK^T already in log2 domain
#define QSCALE (0.08838834764831845f * 1.4426950408889634f)
#define NEG_INF -3.0e38f

typedef __attribute__((ext_vector_type(8))) short short8;  // 8 bf16 = 4 VGPRs
typedef __attribute__((ext_vector_type(4))) float f32x4;

__device__ __forceinline__ float bf2f(u16 u) {
  union { u32 i; float f; } c; c.i = ((u32)u) << 16; return c.f;
}
__device__ __forceinline__ u16 f2bf(float f) {
  union { float f; u32 i; } c; c.f = f;
  u32 x = c.i;
  u32 r = x + 0x7fffu + ((x >> 16) & 1u);  // RNE
  return (u16)(r >> 16);
}

#if __has_builtin(__builtin_amdgcn_exp2f)
__device__ __forceinline__ float exp2_hw(float x) { return __builtin_amdgcn_exp2f(x); }
#else
__device__ __forceinline__ float exp2_hw(float x) { return exp2f(x); }
#endif

// packed f32x2 -> bf16x2 (RNE), single VOP3
__device__ __forceinline__ u32 cvt_pk_bf16(float a, float b) {
  u32 r;
  asm("v_cvt_pk_bf16_f32 %0, %1, %2" : "=v"(r) : "v"(a), "v"(b));
  return r;
}

__device__ __forceinline__ void gload16(const u16* g, u16* l) {
  __builtin_amdgcn_global_load_lds(
      (const __attribute__((address_space(1))) u32*)g,
      (__attribute__((address_space(3))) u32*)l, 16, 0, 0);
}

// ---------------- f32 -> bf16 elementwise convert ---------------------------
__global__ __launch_bounds__(256) void k_cvt(const float* __restrict__ src,
                                             u16* __restrict__ dst) {
  int i = (blockIdx.x * 256 + threadIdx.x) * 8;
  float4 v0 = *(const float4*)(src + i);
  float4 v1 = *(const float4*)(src + i + 4);
  ushort4 w0, w1;
  w0.x = f2bf(v0.x); w0.y = f2bf(v0.y); w0.z = f2bf(v0.z); w0.w = f2bf(v0.w);
  w1.x = f2bf(v1.x); w1.y = f2bf(v1.y); w1.z = f2bf(v1.z); w1.w = f2bf(v1.w);
  *(ushort4*)(dst + i) = w0;
  *(ushort4*)(dst + i + 4) = w1;
}

// ------- transpose + convert body: src[K][N] f32 -> dst[N][K] bf16 ----------
__device__ __forceinline__ void transpose_body(const float* __restrict__ src,
                                               u16* __restrict__ dst,
                                               int N, int K, int nt, int kt,
                                               int t) {
  __shared__ float T[64][65];
#pragma unroll
  for (int it = 0; it < 4; ++it) {
    int r = it * 16 + (t >> 4), c = (t & 15) * 4;
    float4 v = *(const float4*)(src + (size_t)(kt + r) * N + nt + c);
    T[r][c] = v.x; T[r][c + 1] = v.y; T[r][c + 2] = v.z; T[r][c + 3] = v.w;
  }
  __syncthreads();
#pragma unroll
  for (int it = 0; it < 2; ++it) {
    int n = it * 32 + (t >> 3), k8 = (t & 7) * 8;
    ushort4 w0, w1;
    w0.x = f2bf(T[k8 + 0][n]); w0.y = f2bf(T[k8 + 1][n]);
    w0.z = f2bf(T[k8 + 2][n]); w0.w = f2bf(T[k8 + 3][n]);
    w1.x = f2bf(T[k8 + 4][n]); w1.y = f2bf(T[k8 + 5][n]);
    w1.z = f2bf(T[k8 + 6][n]); w1.w = f2bf(T[k8 + 7][n]);
    *(ushort4*)(dst + (size_t)(nt + n) * K + kt + k8) = w0;
    *(ushort4*)(dst + (size_t)(nt + n) * K + kt + k8 + 4) = w1;
  }
}

__global__ __launch_bounds__(256) void k_transpose(const float* __restrict__ src,
                                                   u16* __restrict__ dst,
                                                   int N, int K) {
  transpose_body(src, dst, N, K, blockIdx.x * 64, blockIdx.y * 64, threadIdx.x);
}

// merged Wq|Wk|Wv transpose (one launch)
__global__ __launch_bounds__(256) void k_transpose_qkv(const float* __restrict__ Wq,
                                                       const float* __restrict__ Wk,
                                                       const float* __restrict__ Wv,
                                                       u16* __restrict__ WT) {
  const int bx = blockIdx.x;
  const float* src; u16* dst; int N, nt;
  if (bx < 32)      { src = Wq; dst = WT;                    N = 2048; nt = bx * 64; }
  else if (bx < 40) { src = Wk; dst = WT + 2048ull * 2048;   N = 512;  nt = (bx - 32) * 64; }
  else              { src = Wv; dst = WT + 2560ull * 2048;   N = 512;  nt = (bx - 40) * 64; }
  transpose_body(src, dst, N, 2048, nt, blockIdx.y * 64, threadIdx.x);
}

// ------- V transpose: QKV V-section [s][2560+gd] bf16 -> Vt[gd][s] bf16 -----
__global__ __launch_bounds__(256) void k_vt(const u16* __restrict__ QKV,
                                            u16* __restrict__ Vt) {
  __shared__ u16 T[64][66];
  const int t = threadIdx.x;
  const int s0 = blockIdx.x * 64, d0 = blockIdx.y * 64;
#pragma unroll
  for (int it = 0; it < 4; ++it) {
    int r = it * 16 + (t >> 4), c = (t & 15) * 4;
    ushort4 v = *(const ushort4*)(QKV + (size_t)(s0 + r) * QKVP + 2560 + d0 + c);
    T[r][c] = v.x; T[r][c + 1] = v.y; T[r][c + 2] = v.z; T[r][c + 3] = v.w;
  }
  __syncthreads();
#pragma unroll
  for (int it = 0; it < 4; ++it) {
    int dd = it * 16 + (t >> 4), sc = (t & 15) * 4;
    ushort4 w;
    w.x = T[sc + 0][dd]; w.y = T[sc + 1][dd];
    w.z = T[sc + 2][dd]; w.w = T[sc + 3][dd];
    *(ushort4*)(Vt + (size_t)(d0 + dd) * S + s0 + sc) = w;
  }
}

// ------- MFMA GEMM: BM=64 x BN=128, BK=64, 2-phase prefetch, XOR swizzle ----
// R5's proven BK=64 swizzle machinery, retiled for occupancy: LDS 48KB
// (As 16KB + Bs 32KB, dbuf) -> 3 blocks/CU fit; grids become exact multiples
// of 256 CUs (QKV 24x32=768=3.0/CU, Wo 16x32=512=2.0/CU). Per-wave MFMA per
// barrier stays 32 (wave owns 64x32 output: acc[4][2]).
__global__ __launch_bounds__(256) void k_gemm_mfma(const u16* __restrict__ A,
                                                   const u16* __restrict__ BT,
                                                   void* __restrict__ Cout,
                                                   int N, int K, int out_bf16) {
  __shared__ __align__(16) u16 As[2][64 * 64];
  __shared__ __align__(16) u16 Bs[2][128 * 64];
  const int t = threadIdx.x, w = t >> 6, lane = t & 63;
  const int l15 = lane & 15, quad = lane >> 4;
  const int m0 = blockIdx.y * 64, n0 = blockIdx.x * 128;

  // staging: per issue, wave covers 8 rows (8 lanes/row, 16B each).
  const int srow = lane >> 3;                       // 0..7 within issue
  const int schunk = (lane & 7) ^ srow;             // pre-swizzled source chunk
  const u16* Agb = A + (size_t)(m0 + w * 8 + srow) * K + schunk * 8;
  const u16* Bgb = BT + (size_t)(n0 + w * 8 + srow) * K + schunk * 8;

  f32x4 acc[4][2];
#pragma unroll
  for (int i = 0; i < 4; ++i)
#pragma unroll
    for (int j = 0; j < 2; ++j) acc[i][j] = (f32x4){0.f, 0.f, 0.f, 0.f};

  auto STAGE = [&](int k0, int b) {
#pragma unroll
    for (int it = 0; it < 2; ++it)
      gload16(Agb + (size_t)it * 32 * K + k0, &As[b][(w * 8 + it * 32) * 64]);
#pragma unroll
    for (int it = 0; it < 4; ++it)
      gload16(Bgb + (size_t)it * 32 * K + k0, &Bs[b][(w * 8 + it * 32) * 64]);
  };

  STAGE(0, 0);
  __syncthreads();  // buf0 ready
  int cur = 0;
  for (int k0 = 0; k0 < K; k0 += 64) {
    if (k0 + 64 < K) STAGE(k0 + 64, cur ^ 1);  // issue next tile early

    short8 af[4][2], bf[2][2];
#pragma unroll
    for (int k2 = 0; k2 < 2; ++k2) {
      int ch = (k2 * 4 + quad) ^ (l15 & 7);
#pragma unroll
      for (int i = 0; i < 4; ++i)
        af[i][k2] = *(const short8*)&As[cur][(i * 16 + l15) * 64 + ch * 8];
#pragma unroll
      for (int j = 0; j < 2; ++j)
        bf[j][k2] = *(const short8*)&Bs[cur][(w * 32 + j * 16 + l15) * 64 + ch * 8];
    }
#pragma unroll
    for (int k2 = 0; k2 < 2; ++k2)
#pragma unroll
      for (int i = 0; i < 4; ++i)
#pragma unroll
        for (int j = 0; j < 2; ++j)
          acc[i][j] = __builtin_amdgcn_mfma_f32_16x16x32_bf16(af[i][k2], bf[j][k2], acc[i][j], 0, 0, 0);

    __syncthreads();  // drains prefetch + all waves done reading cur
    cur ^= 1;
  }

  if (out_bf16) {
    u16* C = (u16*)Cout;
#pragma unroll
    for (int i = 0; i < 4; ++i)
#pragma unroll
      for (int j = 0; j < 2; ++j) {
        int col = n0 + w * 32 + j * 16 + l15;
#pragma unroll
        for (int r = 0; r < 4; ++r)
          C[(size_t)(m0 + i * 16 + quad * 4 + r) * N + col] = f2bf(acc[i][j][r]);
      }
  } else {
    float* C = (float*)Cout;
#pragma unroll
    for (int i = 0; i < 4; ++i)
#pragma unroll
      for (int j = 0; j < 2; ++j) {
        int col = n0 + w * 32 + j * 16 + l15;
#pragma unroll
        for (int r = 0; r < 4; ++r)
          C[(size_t)(m0 + i * 16 + quad * 4 + r) * N + col] = acc[i][j][r];
      }
  }
}

// ------------- per-(s,head) RMSNorm + RoPE, Q and K in one launch (R1) ------
__global__ __launch_bounds__(128) void k_norm_rope(u16* __restrict__ QKV,
                                                   const float* __restrict__ qsc,
                                                   const float* __restrict__ ksc,
                                                   const float* __restrict__ cosp,
                                                   const float* __restrict__ sinp) {
  const int s = blockIdx.x, hh = blockIdx.y, d = threadIdx.x;
  u16* row; const float* sc; float scale;
  if (hh < NH) { row = QKV + (size_t)s * QKVP + hh * D;            sc = qsc; scale = QSCALE; }
  else         { row = QKV + (size_t)s * QKVP + 2048 + (hh - NH) * D; sc = ksc; scale = 1.0f; }
  float x = bf2f(row[d]);
  float v = x * x;
#pragma unroll
  for (int o = 32; o; o >>= 1) v += __shfl_xor(v, o, 64);
  __shared__ float red[2];
  if ((d & 63) == 0) red[d >> 6] = v;
  __syncthreads();
  float var = (red[0] + red[1]) * (1.0f / 128.0f);
  float rinv = rsqrtf(var + 1e-6f) * scale;
  float xn = x * rinv * sc[d];
  __shared__ float sh[D];
  sh[d] = xn;
  __syncthreads();
  float rot = (d < 64) ? -sh[d + 64] : sh[d - 64];
  row[d] = f2bf(xn * cosp[s * D + d] + rot * sinp[s * D + d]);
}

// ---------------- flash attention (R1-proven): pipelined K-DMA --------------
// Block: 256 thr (4 waves) = 64-row q-tile of one head.
// K: global_load_lds into double-buffered unpadded LDS, SOURCE-chunk-swizzled
//    (chunk ^= row&7) so frag reads are conflict-free; DMA for tile jt+1
//    issues during compute of jt -> latency hidden behind compute.
// V: register-prefetched (ping-pong), written XOR-swizzled.
// P: packed bf16 pairs -> 4 ds_write_b64 + 2 ds_read_b128 per tile/wave.
#define KP 128   // K LDS row pitch (u16), unpadded (DMA requirement)
#define PTP 72   // P pitch (u16): b64-write / b128-read aligned

__global__ __launch_bounds__(256) void k_flash(const u16* __restrict__ QKV,
                                               const u16* __restrict__ Vt,
                                               u16* __restrict__ O) {
  const int h = blockIdx.y, g = h >> 2;
  const int qt = (h < 8) ? (31 - (int)blockIdx.x) : (int)blockIdx.x;
  const int t = threadIdx.x;
  const int w = t >> 6, lane = t & 63, l15 = lane & 15, quad = lane >> 4;

  __shared__ __align__(16) u16 Klds[2][64 * KP];
  __shared__ __align__(16) u16 Vlds[128 * 64];     // [d][key], XOR-swizzled
  __shared__ __align__(16) u16 Pt[4][16 * PTP];    // [qcol][key] per wave

  const int qbase = qt * 64 + w * 16;
  const int qrow = qbase + l15;

  short8 qf[4];
  {
    const u16* qp = QKV + (size_t)qrow * QKVP + h * D + quad * 8;
#pragma unroll
    for (int c = 0; c < 4; ++c) qf[c] = *(const short8*)(qp + c * 32);
  }

  float m = NEG_INF, l = 0.f;
  f32x4 oacc[8];
#pragma unroll
  for (int nc = 0; nc < 8; ++nc) oacc[nc] = (f32x4){0.f, 0.f, 0.f, 0.f};

  const int nt = qt + 1;
  const int dd = t >> 3, cc = t & 7;  // V staging coords

  auto KLOAD = [&](int j0, int b) {  // DMA 4 rows per wave per issue
#pragma unroll
    for (int it = 0; it < 4; ++it) {
      int rl = w * 16 + it * 4 + quad;                 // tile-local key row
      int gchunk = (lane & 15) ^ (rl & 7);             // source swizzle
      const u16* gp = QKV + (size_t)(j0 + rl) * QKVP + 2048 + g * D + gchunk * 8;
      gload16(gp, &Klds[b][(w * 16 + it * 4) * KP]);
    }
  };
  auto VLOAD = [&](int j0, uint4* vr) {
#pragma unroll
    for (int it = 0; it < 4; ++it)
      vr[it] = *(const uint4*)(Vt + (size_t)(g * D + dd + it * 32) * S + j0 + cc * 8);
  };
  auto VWRITE = [&](uint4* vr) {
#pragma unroll
    for (int it = 0; it < 4; ++it) {
      int d = dd + it * 32;
      *(uint4*)&Vlds[d * 64 + ((cc ^ (d & 7)) * 8)] = vr[it];
    }
  };
  auto COMPUTE = [&](int jt, int b) {
    const int j0 = jt * 64;
    // ---- S^T = K x Q^T : row = key (quad*4+r +16sub), col = q-row (l15) ----
    f32x4 sa[4];
#pragma unroll
    for (int sub = 0; sub < 4; ++sub) {
      f32x4 acc = {0.f, 0.f, 0.f, 0.f};
#pragma unroll
      for (int c = 0; c < 4; ++c) {
        int ch = (c * 4 + quad) ^ (l15 & 7);  // undo source swizzle
        short8 kf = *(const short8*)&Klds[b][(sub * 16 + l15) * KP + ch * 8];
        acc = __builtin_amdgcn_mfma_f32_16x16x32_bf16(kf, qf[c], acc, 0, 0, 0);
      }
      sa[sub] = acc;
    }
    if (jt == nt - 1) {  // causal mask, diagonal tile only
#pragma unroll
      for (int sub = 0; sub < 4; ++sub) {
        int keyb = j0 + sub * 16 + quad * 4;
#pragma unroll
        for (int r = 0; r < 4; ++r)
          if (keyb + r > qrow) sa[sub][r] = NEG_INF;
      }
    }
    // ---- online softmax in exp2 domain (scores pre-scaled by log2e) -------
    float tmax = sa[0][0];
#pragma unroll
    for (int sub = 0; sub < 4; ++sub)
#pragma unroll
      for (int r = 0; r < 4; ++r) tmax = fmaxf(tmax, sa[sub][r]);
    tmax = fmaxf(tmax, __shfl_xor(tmax, 16, 64));
    tmax = fmaxf(tmax, __shfl_xor(tmax, 32, 64));
    float mn = fmaxf(m, tmax);
    float alpha = exp2_hw(m - mn);
    m = mn;
    float rs = 0.f;
#pragma unroll
    for (int sub = 0; sub < 4; ++sub) {
      float p0 = exp2_hw(sa[sub][0] - m);
      float p1 = exp2_hw(sa[sub][1] - m);
      float p2 = exp2_hw(sa[sub][2] - m);
      float p3 = exp2_hw(sa[sub][3] - m);
      rs += (p0 + p1) + (p2 + p3);
      u32 lo = cvt_pk_bf16(p0, p1);
      u32 hi = cvt_pk_bf16(p2, p3);
      *(uint2*)&Pt[w][l15 * PTP + sub * 16 + quad * 4] = make_uint2(lo, hi);
    }
    rs += __shfl_xor(rs, 16, 64);
    rs += __shfl_xor(rs, 32, 64);
    l = l * alpha + rs;
#pragma unroll
    for (int nc = 0; nc < 8; ++nc) {
      oacc[nc][0] *= alpha; oacc[nc][1] *= alpha;
      oacc[nc][2] *= alpha; oacc[nc][3] *= alpha;
    }
    // ---- O^T += V^T x P^T ----
#pragma unroll
    for (int kc = 0; kc < 2; ++kc) {
      short8 pf = *(const short8*)&Pt[w][l15 * PTP + kc * 32 + quad * 8];
#pragma unroll
      for (int nc = 0; nc < 8; ++nc) {
        int d = nc * 16 + l15;
        short8 vf = *(const short8*)&Vlds[d * 64 + (((kc * 4 + quad) ^ (d & 7)) * 8)];
        oacc[nc] = __builtin_amdgcn_mfma_f32_16x16x32_bf16(vf, pf, oacc[nc], 0, 0, 0);
      }
    }
  };

  uint4 vrA[4], vrB[4];
  KLOAD(0, 0);
  VLOAD(0, vrA);
  for (int jt = 0; jt < nt; jt += 2) {
    __syncthreads();                       // prev compute done; K(jt) DMA drained
    VWRITE(vrA);
    __syncthreads();                       // V(jt) visible
    if (jt + 1 < nt) { KLOAD((jt + 1) * 64, 1); VLOAD((jt + 1) * 64, vrB); }
    COMPUTE(jt, 0);
    if (jt + 1 < nt) {
      __syncthreads();
      VWRITE(vrB);
      __syncthreads();
      if (jt + 2 < nt) { KLOAD((jt + 2) * 64, 0); VLOAD((jt + 2) * 64, vrA); }
      COMPUTE(jt + 1, 1);
    }
  }

  // ---- epilogue: O[q][d] = O^T / l ----
  float inv = 1.0f / l;
  u16* orow = O + (size_t)qrow * HID + h * D;
#pragma unroll
  for (int nc = 0; nc < 8; ++nc) {
    ushort4 wv;
    wv.x = f2bf(oacc[nc][0] * inv); wv.y = f2bf(oacc[nc][1] * inv);
    wv.z = f2bf(oacc[nc][2] * inv); wv.w = f2bf(oacc[nc][3] * inv);
    *(ushort4*)(orow + nc * 16 + quad * 4) = wv;
  }
}

// ---------------- final RMSNorm over HIDDEN=2048 ----------------------------
__device__ __forceinline__ float blockSum256(float v, float* red, int t) {
#pragma unroll
  for (int o = 32; o; o >>= 1) v += __shfl_xor(v, o, 64);
  if ((t & 63) == 0) red[t >> 6] = v;
  __syncthreads();
  v = red[0] + red[1] + red[2] + red[3];
  __syncthreads();
  return v;
}

__global__ __launch_bounds__(256) void k_fnorm(const float* __restrict__ X,
                                               const float* __restrict__ sc,
                                               float* __restrict__ out) {
  const int s = blockIdx.x, t = threadIdx.x;
  const float* row = X + (size_t)s * HID;
  float4 r0 = *(const float4*)(row + t * 8);
  float4 r1 = *(const float4*)(row + t * 8 + 4);
  float x[8] = {r0.x, r0.y, r0.z, r0.w, r1.x, r1.y, r1.z, r1.w};
  float ss = 0.f;
#pragma unroll
  for (int ii = 0; ii < 8; ++ii) ss += x[ii] * x[ii];
  __shared__ float red[4];
  float tot = blockSum256(ss, red, t);
  float rinv = rsqrtf(tot * (1.0f / 2048.0f) + 1e-6f);
  float4 s0 = *(const float4*)(sc + t * 8);
  float4 s1 = *(const float4*)(sc + t * 8 + 4);
  float4 w0 = make_float4(x[0] * rinv * s0.x, x[1] * rinv * s0.y,
                          x[2] * rinv * s0.z, x[3] * rinv * s0.w);
  float4 w1 = make_float4(x[4] * rinv * s1.x, x[5] * rinv * s1.y,
                          x[6] * rinv * s1.z, x[7] * rinv * s1.w);
  *(float4*)(out + (size_t)s * HID + t * 8) = w0;
  *(float4*)(out + (size_t)s * HID + t * 8 + 4) = w1;
}

extern "C" void kernel_launch(void* const* d_in, const int* in_sizes, int n_in,
                              void* d_out, int out_size, void* d_ws, size_t ws_size,
                              hipStream_t stream) {
  const float* hidden = (const float*)d_in[0];
  const float* cosp   = (const float*)d_in[1];
  const float* sinp   = (const float*)d_in[2];
  const float* Wq     = (const float*)d_in[3];
  const float* Wk     = (const float*)d_in[4];
  const float* Wv     = (const float*)d_in[5];
  const float* Wo     = (const float*)d_in[6];
  const float* qsc    = (const float*)d_in[7];
  const float* ksc    = (const float*)d_in[8];
  const float* lsc    = (const float*)d_in[9];
  float* out = (float*)d_out;

  char* ws = (char*)d_ws;
  u16*   Hb  = (u16*)(ws);                   // [S][HID] bf16, 8 MiB
  u16*   WoT = (u16*)(ws);                   // overlays Hb (after QKV GEMM)
  u16*   WT  = (u16*)(ws + (8ull << 20));    // [3072][2048] bf16, 12 MiB
  u16*   An  = (u16*)(ws + (8ull << 20));    // overlays WT (after QKV GEMM)
  u16*   QKV = (u16*)(ws + (20ull << 20));   // [S][3072] bf16, 12 MiB
  float* Ob  = (float*)(ws + (20ull << 20)); // overlays QKV (after flash)
  u16*   Vtb = (u16*)(ws + (32ull << 20));   // [512][2048] bf16, 2 MiB

  k_cvt<<<S * HID / (256 * 8), 256, 0, stream>>>(hidden, Hb);
  k_transpose_qkv<<<dim3(48, 32), 256, 0, stream>>>(Wq, Wk, Wv, WT);
  k_gemm_mfma<<<dim3(24, 32), 256, 0, stream>>>(Hb, WT, QKV, QKVP, 2048, 1);
  k_transpose<<<dim3(32, 32), 256, 0, stream>>>(Wo, WoT, 2048, 2048);  // Hb dead
  k_norm_rope<<<dim3(S, NH + NKV), 128, 0, stream>>>(QKV, qsc, ksc, cosp, sinp);
  k_vt<<<dim3(32, 8), 256, 0, stream>>>(QKV, Vtb);
  k_flash<<<dim3(32, NH), 256, 0, stream>>>(QKV, Vtb, An);
  k_gemm_mfma<<<dim3(16, 32), 256, 0, stream>>>(An, WoT, Ob, 2048, 2048, 0);
  k_fnorm<<<S, 256, 0, stream>>>(Ob, lsc, out);
}

// Round 10
// 285.410 us; speedup vs baseline: 1.1713x; 1.0366x over previous
//
#include <hip/hip_runtime.h>

typedef unsigned short u16;
typedef unsigned int u32;

#define S 2048
#define HID 2048
#define NH 16
#define NKV 4
#define D 128
#define QKVP 3072  // QKV buffer pitch (Q|K|V concat per row)
// 1/sqrt(128) * log2(e): scores come out of QK^T already in log2 domain
#define QSCALE (0.08838834764831845f * 1.4426950408889634f)
#define NEG_INF -3.0e38f

typedef __attribute__((ext_vector_type(8))) short short8;  // 8 bf16 = 4 VGPRs
typedef __attribute__((ext_vector_type(4))) float f32x4;

__device__ __forceinline__ float bf2f(u16 u) {
  union { u32 i; float f; } c; c.i = ((u32)u) << 16; return c.f;
}
__device__ __forceinline__ u16 f2bf(float f) {
  union { float f; u32 i; } c; c.f = f;
  u32 x = c.i;
  u32 r = x + 0x7fffu + ((x >> 16) & 1u);  // RNE
  return (u16)(r >> 16);
}

#if __has_builtin(__builtin_amdgcn_exp2f)
__device__ __forceinline__ float exp2_hw(float x) { return __builtin_amdgcn_exp2f(x); }
#else
__device__ __forceinline__ float exp2_hw(float x) { return exp2f(x); }
#endif

// packed f32x2 -> bf16x2 (RNE), single VOP3
__device__ __forceinline__ u32 cvt_pk_bf16(float a, float b) {
  u32 r;
  asm("v_cvt_pk_bf16_f32 %0, %1, %2" : "=v"(r) : "v"(a), "v"(b));
  return r;
}

__device__ __forceinline__ void gload16(const u16* g, u16* l) {
  __builtin_amdgcn_global_load_lds(
      (const __attribute__((address_space(1))) u32*)g,
      (__attribute__((address_space(3))) u32*)l, 16, 0, 0);
}

// ------- transpose + convert body: src[K][N] f32 -> dst[N][K] bf16 ----------
__device__ __forceinline__ void transpose_body(const float* __restrict__ src,
                                               u16* __restrict__ dst,
                                               int N, int K, int nt, int kt,
                                               int t) {
  __shared__ float T[64][65];
#pragma unroll
  for (int it = 0; it < 4; ++it) {
    int r = it * 16 + (t >> 4), c = (t & 15) * 4;
    float4 v = *(const float4*)(src + (size_t)(kt + r) * N + nt + c);
    T[r][c] = v.x; T[r][c + 1] = v.y; T[r][c + 2] = v.z; T[r][c + 3] = v.w;
  }
  __syncthreads();
#pragma unroll
  for (int it = 0; it < 2; ++it) {
    int n = it * 32 + (t >> 3), k8 = (t & 7) * 8;
    ushort4 w0, w1;
    w0.x = f2bf(T[k8 + 0][n]); w0.y = f2bf(T[k8 + 1][n]);
    w0.z = f2bf(T[k8 + 2][n]); w0.w = f2bf(T[k8 + 3][n]);
    w1.x = f2bf(T[k8 + 4][n]); w1.y = f2bf(T[k8 + 5][n]);
    w1.z = f2bf(T[k8 + 6][n]); w1.w = f2bf(T[k8 + 7][n]);
    *(ushort4*)(dst + (size_t)(nt + n) * K + kt + k8) = w0;
    *(ushort4*)(dst + (size_t)(nt + n) * K + kt + k8 + 4) = w1;
  }
}

// ------- merged preprocessing: hidden f32->bf16 cvt + Wq|Wk|Wv transpose ----
// (independent outputs Hb / WT; one launch removes 1 gap + tail idle)
__global__ __launch_bounds__(256) void k_pre(const float* __restrict__ hidden,
                                             u16* __restrict__ Hb,
                                             const float* __restrict__ Wq,
                                             const float* __restrict__ Wk,
                                             const float* __restrict__ Wv,
                                             u16* __restrict__ WT) {
  const int bx = blockIdx.x, t = threadIdx.x;
  if (bx < 2048) {  // cvt: 2048 blocks x 2048 elems
    int i = (bx * 256 + t) * 8;
    float4 v0 = *(const float4*)(hidden + i);
    float4 v1 = *(const float4*)(hidden + i + 4);
    ushort4 w0, w1;
    w0.x = f2bf(v0.x); w0.y = f2bf(v0.y); w0.z = f2bf(v0.z); w0.w = f2bf(v0.w);
    w1.x = f2bf(v1.x); w1.y = f2bf(v1.y); w1.z = f2bf(v1.z); w1.w = f2bf(v1.w);
    *(ushort4*)(Hb + i) = w0;
    *(ushort4*)(Hb + i + 4) = w1;
    return;
  }
  const int id = bx - 2048;            // 0..1535
  const int x = id % 48, y = id / 48;  // old dim3(48,32)
  const float* src; u16* dst; int N, nt;
  if (x < 32)      { src = Wq; dst = WT;                    N = 2048; nt = x * 64; }
  else if (x < 40) { src = Wk; dst = WT + 2048ull * 2048;   N = 512;  nt = (x - 32) * 64; }
  else             { src = Wv; dst = WT + 2560ull * 2048;   N = 512;  nt = (x - 40) * 64; }
  transpose_body(src, dst, N, 2048, nt, y * 64, t);
}

__global__ __launch_bounds__(256) void k_transpose(const float* __restrict__ src,
                                                   u16* __restrict__ dst,
                                                   int N, int K) {
  transpose_body(src, dst, N, K, blockIdx.x * 64, blockIdx.y * 64, threadIdx.x);
}

// ------- V transpose: QKV V-section [s][2560+gd] bf16 -> Vt[gd][s] bf16 -----
__global__ __launch_bounds__(256) void k_vt(const u16* __restrict__ QKV,
                                            u16* __restrict__ Vt) {
  __shared__ u16 T[64][66];
  const int t = threadIdx.x;
  const int s0 = blockIdx.x * 64, d0 = blockIdx.y * 64;
#pragma unroll
  for (int it = 0; it < 4; ++it) {
    int r = it * 16 + (t >> 4), c = (t & 15) * 4;
    ushort4 v = *(const ushort4*)(QKV + (size_t)(s0 + r) * QKVP + 2560 + d0 + c);
    T[r][c] = v.x; T[r][c + 1] = v.y; T[r][c + 2] = v.z; T[r][c + 3] = v.w;
  }
  __syncthreads();
#pragma unroll
  for (int it = 0; it < 4; ++it) {
    int dd = it * 16 + (t >> 4), sc = (t & 15) * 4;
    ushort4 w;
    w.x = T[sc + 0][dd]; w.y = T[sc + 1][dd];
    w.z = T[sc + 2][dd]; w.w = T[sc + 3][dd];
    *(ushort4*)(Vt + (size_t)(d0 + dd) * S + s0 + sc) = w;
  }
}

// ------- MFMA GEMM: BM=64 x BN=128, BK=64, 2-phase prefetch, XOR swizzle ----
// (R9-proven) LDS 48KB -> 3 blocks/CU; grids exact multiples of 256 CUs.
__global__ __launch_bounds__(256) void k_gemm_mfma(const u16* __restrict__ A,
                                                   const u16* __restrict__ BT,
                                                   void* __restrict__ Cout,
                                                   int N, int K, int out_bf16) {
  __shared__ __align__(16) u16 As[2][64 * 64];
  __shared__ __align__(16) u16 Bs[2][128 * 64];
  const int t = threadIdx.x, w = t >> 6, lane = t & 63;
  const int l15 = lane & 15, quad = lane >> 4;
  const int m0 = blockIdx.y * 64, n0 = blockIdx.x * 128;

  const int srow = lane >> 3;                       // 0..7 within issue
  const int schunk = (lane & 7) ^ srow;             // pre-swizzled source chunk
  const u16* Agb = A + (size_t)(m0 + w * 8 + srow) * K + schunk * 8;
  const u16* Bgb = BT + (size_t)(n0 + w * 8 + srow) * K + schunk * 8;

  f32x4 acc[4][2];
#pragma unroll
  for (int i = 0; i < 4; ++i)
#pragma unroll
    for (int j = 0; j < 2; ++j) acc[i][j] = (f32x4){0.f, 0.f, 0.f, 0.f};

  auto STAGE = [&](int k0, int b) {
#pragma unroll
    for (int it = 0; it < 2; ++it)
      gload16(Agb + (size_t)it * 32 * K + k0, &As[b][(w * 8 + it * 32) * 64]);
#pragma unroll
    for (int it = 0; it < 4; ++it)
      gload16(Bgb + (size_t)it * 32 * K + k0, &Bs[b][(w * 8 + it * 32) * 64]);
  };

  STAGE(0, 0);
  __syncthreads();  // buf0 ready
  int cur = 0;
  for (int k0 = 0; k0 < K; k0 += 64) {
    if (k0 + 64 < K) STAGE(k0 + 64, cur ^ 1);  // issue next tile early

    short8 af[4][2], bf[2][2];
#pragma unroll
    for (int k2 = 0; k2 < 2; ++k2) {
      int ch = (k2 * 4 + quad) ^ (l15 & 7);
#pragma unroll
      for (int i = 0; i < 4; ++i)
        af[i][k2] = *(const short8*)&As[cur][(i * 16 + l15) * 64 + ch * 8];
#pragma unroll
      for (int j = 0; j < 2; ++j)
        bf[j][k2] = *(const short8*)&Bs[cur][(w * 32 + j * 16 + l15) * 64 + ch * 8];
    }
#pragma unroll
    for (int k2 = 0; k2 < 2; ++k2)
#pragma unroll
      for (int i = 0; i < 4; ++i)
#pragma unroll
        for (int j = 0; j < 2; ++j)
          acc[i][j] = __builtin_amdgcn_mfma_f32_16x16x32_bf16(af[i][k2], bf[j][k2], acc[i][j], 0, 0, 0);

    __syncthreads();  // drains prefetch + all waves done reading cur
    cur ^= 1;
  }

  if (out_bf16) {
    u16* C = (u16*)Cout;
#pragma unroll
    for (int i = 0; i < 4; ++i)
#pragma unroll
      for (int j = 0; j < 2; ++j) {
        int col = n0 + w * 32 + j * 16 + l15;
#pragma unroll
        for (int r = 0; r < 4; ++r)
          C[(size_t)(m0 + i * 16 + quad * 4 + r) * N + col] = f2bf(acc[i][j][r]);
      }
  } else {
    float* C = (float*)Cout;
#pragma unroll
    for (int i = 0; i < 4; ++i)
#pragma unroll
      for (int j = 0; j < 2; ++j) {
        int col = n0 + w * 32 + j * 16 + l15;
#pragma unroll
        for (int r = 0; r < 4; ++r)
          C[(size_t)(m0 + i * 16 + quad * 4 + r) * N + col] = acc[i][j][r];
      }
  }
}

// ------------- RMSNorm + RoPE, one WAVE per (s,head) row --------------------
// lane holds 2 elems (d=2*lane, 2*lane+1); rotate_half via shfl_xor(.,32);
// no LDS, no barriers. Q scaled by 1/sqrt(d)*log2(e) for exp2-domain flash.
__global__ __launch_bounds__(256) void k_norm_rope(u16* __restrict__ QKV,
                                                   const float* __restrict__ qsc,
                                                   const float* __restrict__ ksc,
                                                   const float* __restrict__ cosp,
                                                   const float* __restrict__ sinp) {
  const int s = blockIdx.x;
  const int w = threadIdx.x >> 6, lane = threadIdx.x & 63;
  const int hh = blockIdx.y * 4 + w;
  u16* row; const float* sc; float scale;
  if (hh < NH) { row = QKV + (size_t)s * QKVP + hh * D;               sc = qsc; scale = QSCALE; }
  else         { row = QKV + (size_t)s * QKVP + 2048 + (hh - NH) * D; sc = ksc; scale = 1.0f; }
  const int d0 = lane * 2;
  u32 pr = *(const u32*)(row + d0);
  float x0 = bf2f((u16)(pr & 0xffffu)), x1 = bf2f((u16)(pr >> 16));
  float v = x0 * x0 + x1 * x1;
#pragma unroll
  for (int o = 32; o; o >>= 1) v += __shfl_xor(v, o, 64);
  float rinv = rsqrtf(v * (1.0f / 128.0f) + 1e-6f) * scale;
  float xn0 = x0 * rinv * sc[d0], xn1 = x1 * rinv * sc[d0 + 1];
  float p0 = __shfl_xor(xn0, 32, 64);
  float p1 = __shfl_xor(xn1, 32, 64);
  float sgn = (lane < 32) ? -1.f : 1.f;
  float2 c  = *(const float2*)(cosp + (size_t)s * D + d0);
  float2 sn = *(const float2*)(sinp + (size_t)s * D + d0);
  float o0 = xn0 * c.x + sgn * p0 * sn.x;
  float o1 = xn1 * c.y + sgn * p1 * sn.y;
  *(u32*)(row + d0) = cvt_pk_bf16(o0, o1);
}

// ---------------- flash attention: R1 structure + prefetch AFTER QK^T -------
// Key fix: the compiler inserts a conservative s_waitcnt vmcnt(0) before any
// ds_read of Klds while a global_load_lds is outstanding (can't disambiguate
// the double-buffer halves). R1 issued KLOAD(jt+1) BEFORE compute -> every
// tile drained its own fresh prefetch = full latency exposed. Now the
// prefetch issues AFTER the QK^T Klds reads (zero outstanding VMEM at QK^T
// entry -> no stall) and its latency hides under softmax+Pt+PV before the
// next barrier's drain. Everything else identical to R9.
#define KP 128   // K LDS row pitch (u16), unpadded (DMA requirement)
#define PTP 72   // P pitch (u16): b64-write / b128-read aligned

__global__ __launch_bounds__(256) void k_flash(const u16* __restrict__ QKV,
                                               const u16* __restrict__ Vt,
                                               u16* __restrict__ O) {
  const int h = blockIdx.y, g = h >> 2;
  const int qt = (h < 8) ? (31 - (int)blockIdx.x) : (int)blockIdx.x;
  const int t = threadIdx.x;
  const int w = t >> 6, lane = t & 63, l15 = lane & 15, quad = lane >> 4;

  __shared__ __align__(16) u16 Klds[2][64 * KP];
  __shared__ __align__(16) u16 Vlds[128 * 64];     // [d][key], XOR-swizzled
  __shared__ __align__(16) u16 Pt[4][16 * PTP];    // [qcol][key] per wave

  const int qbase = qt * 64 + w * 16;
  const int qrow = qbase + l15;

  short8 qf[4];
  {
    const u16* qp = QKV + (size_t)qrow * QKVP + h * D + quad * 8;
#pragma unroll
    for (int c = 0; c < 4; ++c) qf[c] = *(const short8*)(qp + c * 32);
  }

  float m = NEG_INF, l = 0.f;
  f32x4 oacc[8];
#pragma unroll
  for (int nc = 0; nc < 8; ++nc) oacc[nc] = (f32x4){0.f, 0.f, 0.f, 0.f};

  const int nt = qt + 1;
  const int dd = t >> 3, cc = t & 7;  // V staging coords

  auto KLOAD = [&](int j0, int b) {  // DMA 4 rows per wave per issue
#pragma unroll
    for (int it = 0; it < 4; ++it) {
      int rl = w * 16 + it * 4 + quad;                 // tile-local key row
      int gchunk = (lane & 15) ^ (rl & 7);             // source swizzle
      const u16* gp = QKV + (size_t)(j0 + rl) * QKVP + 2048 + g * D + gchunk * 8;
      gload16(gp, &Klds[b][(w * 16 + it * 4) * KP]);
    }
  };
  auto VLOAD = [&](int j0, uint4* vr) {
#pragma unroll
    for (int it = 0; it < 4; ++it)
      vr[it] = *(const uint4*)(Vt + (size_t)(g * D + dd + it * 32) * S + j0 + cc * 8);
  };
  auto VWRITE = [&](uint4* vr) {
#pragma unroll
    for (int it = 0; it < 4; ++it) {
      int d = dd + it * 32;
      *(uint4*)&Vlds[d * 64 + ((cc ^ (d & 7)) * 8)] = vr[it];
    }
  };
  // QK^T only: reads Klds[b] (no outstanding VMEM at entry -> no drain stall)
  auto QKT = [&](int b, f32x4* sa) {
#pragma unroll
    for (int sub = 0; sub < 4; ++sub) {
      f32x4 acc = {0.f, 0.f, 0.f, 0.f};
#pragma unroll
      for (int c = 0; c < 4; ++c) {
        int ch = (c * 4 + quad) ^ (l15 & 7);  // undo source swizzle
        short8 kf = *(const short8*)&Klds[b][(sub * 16 + l15) * KP + ch * 8];
        acc = __builtin_amdgcn_mfma_f32_16x16x32_bf16(kf, qf[c], acc, 0, 0, 0);
      }
      sa[sub] = acc;
    }
  };
  // mask + softmax + Pt + PV: covers the just-issued prefetch's latency
  auto SMPV = [&](int jt, f32x4* sa) {
    const int j0 = jt * 64;
    if (jt == nt - 1) {  // causal mask, diagonal tile only
#pragma unroll
      for (int sub = 0; sub < 4; ++sub) {
        int keyb = j0 + sub * 16 + quad * 4;
#pragma unroll
        for (int r = 0; r < 4; ++r)
          if (keyb + r > qrow) sa[sub][r] = NEG_INF;
      }
    }
    float tmax = sa[0][0];
#pragma unroll
    for (int sub = 0; sub < 4; ++sub)
#pragma unroll
      for (int r = 0; r < 4; ++r) tmax = fmaxf(tmax, sa[sub][r]);
    tmax = fmaxf(tmax, __shfl_xor(tmax, 16, 64));
    tmax = fmaxf(tmax, __shfl_xor(tmax, 32, 64));
    float mn = fmaxf(m, tmax);
    float alpha = exp2_hw(m - mn);
    m = mn;
    float rs = 0.f;
#pragma unroll
    for (int sub = 0; sub < 4; ++sub) {
      float p0 = exp2_hw(sa[sub][0] - m);
      float p1 = exp2_hw(sa[sub][1] - m);
      float p2 = exp2_hw(sa[sub][2] - m);
      float p3 = exp2_hw(sa[sub][3] - m);
      rs += (p0 + p1) + (p2 + p3);
      u32 lo = cvt_pk_bf16(p0, p1);
      u32 hi = cvt_pk_bf16(p2, p3);
      *(uint2*)&Pt[w][l15 * PTP + sub * 16 + quad * 4] = make_uint2(lo, hi);
    }
    rs += __shfl_xor(rs, 16, 64);
    rs += __shfl_xor(rs, 32, 64);
    l = l * alpha + rs;
#pragma unroll
    for (int nc = 0; nc < 8; ++nc) {
      oacc[nc][0] *= alpha; oacc[nc][1] *= alpha;
      oacc[nc][2] *= alpha; oacc[nc][3] *= alpha;
    }
#pragma unroll
    for (int kc = 0; kc < 2; ++kc) {
      short8 pf = *(const short8*)&Pt[w][l15 * PTP + kc * 32 + quad * 8];
#pragma unroll
      for (int nc = 0; nc < 8; ++nc) {
        int d = nc * 16 + l15;
        short8 vf = *(const short8*)&Vlds[d * 64 + (((kc * 4 + quad) ^ (d & 7)) * 8)];
        oacc[nc] = __builtin_amdgcn_mfma_f32_16x16x32_bf16(vf, pf, oacc[nc], 0, 0, 0);
      }
    }
  };

  uint4 vrA[4], vrB[4];
  f32x4 sa[4];
  KLOAD(0, 0);
  VLOAD(0, vrA);
  for (int jt = 0; jt < nt; jt += 2) {
    __syncthreads();                       // drains K(jt) DMA + all VMEM
    VWRITE(vrA);
    __syncthreads();                       // V(jt) visible
    QKT(0, sa);                            // no outstanding VMEM -> no stall
    if (jt + 1 < nt) { KLOAD((jt + 1) * 64, 1); VLOAD((jt + 1) * 64, vrB); }
    SMPV(jt, sa);                          // covers prefetch latency
    if (jt + 1 < nt) {
      __syncthreads();                     // drains K(jt+1)+V(jt+1), covered
      VWRITE(vrB);
      __syncthreads();
      QKT(1, sa);
      if (jt + 2 < nt) { KLOAD((jt + 2) * 64, 0); VLOAD((jt + 2) * 64, vrA); }
      SMPV(jt + 1, sa);
    }
  }

  // ---- epilogue: O[q][d] = O^T / l ----
  float inv = 1.0f / l;
  u16* orow = O + (size_t)qrow * HID + h * D;
#pragma unroll
  for (int nc = 0; nc < 8; ++nc) {
    ushort4 wv;
    wv.x = f2bf(oacc[nc][0] * inv); wv.y = f2bf(oacc[nc][1] * inv);
    wv.z = f2bf(oacc[nc][2] * inv); wv.w = f2bf(oacc[nc][3] * inv);
    *(ushort4*)(orow + nc * 16 + quad * 4) = wv;
  }
}

// ---------------- final RMSNorm over HIDDEN=2048 ----------------------------
__device__ __forceinline__ float blockSum256(float v, float* red, int t) {
#pragma unroll
  for (int o = 32; o; o >>= 1) v += __shfl_xor(v, o, 64);
  if ((t & 63) == 0) red[t >> 6] = v;
  __syncthreads();
  v = red[0] + red[1] + red[2] + red[3];
  __syncthreads();
  return v;
}

__global__ __launch_bounds__(256) void k_fnorm(const float* __restrict__ X,
                                               const float* __restrict__ sc,
                                               float* __restrict__ out) {
  const int s = blockIdx.x, t = threadIdx.x;
  const float* row = X + (size_t)s * HID;
  float4 r0 = *(const float4*)(row + t * 8);
  float4 r1 = *(const float4*)(row + t * 8 + 4);
  float x[8] = {r0.x, r0.y, r0.z, r0.w, r1.x, r1.y, r1.z, r1.w};
  float ss = 0.f;
#pragma unroll
  for (int ii = 0; ii < 8; ++ii) ss += x[ii] * x[ii];
  __shared__ float red[4];
  float tot = blockSum256(ss, red, t);
  float rinv = rsqrtf(tot * (1.0f / 2048.0f) + 1e-6f);
  float4 s0 = *(const float4*)(sc + t * 8);
  float4 s1 = *(const float4*)(sc + t * 8 + 4);
  float4 w0 = make_float4(x[0] * rinv * s0.x, x[1] * rinv * s0.y,
                          x[2] * rinv * s0.z, x[3] * rinv * s0.w);
  float4 w1 = make_float4(x[4] * rinv * s1.x, x[5] * rinv * s1.y,
                          x[6] * rinv * s1.z, x[7] * rinv * s1.w);
  *(float4*)(out + (size_t)s * HID + t * 8) = w0;
  *(float4*)(out + (size_t)s * HID + t * 8 + 4) = w1;
}

extern "C" void kernel_launch(void* const* d_in, const int* in_sizes, int n_in,
                              void* d_out, int out_size, void* d_ws, size_t ws_size,
                              hipStream_t stream) {
  const float* hidden = (const float*)d_in[0];
  const float* cosp   = (const float*)d_in[1];
  const float* sinp   = (const float*)d_in[2];
  const float* Wq     = (const float*)d_in[3];
  const float* Wk     = (const float*)d_in[4];
  const float* Wv     = (const float*)d_in[5];
  const float* Wo     = (const float*)d_in[6];
  const float* qsc    = (const float*)d_in[7];
  const float* ksc    = (const float*)d_in[8];
  const float* lsc    = (const float*)d_in[9];
  float* out = (float*)d_out;

  char* ws = (char*)d_ws;
  u16*   Hb  = (u16*)(ws);                   // [S][HID] bf16, 8 MiB
  u16*   WoT = (u16*)(ws);                   // overlays Hb (after QKV GEMM)
  u16*   WT  = (u16*)(ws + (8ull << 20));    // [3072][2048] bf16, 12 MiB
  u16*   An  = (u16*)(ws + (8ull << 20));    // overlays WT (after QKV GEMM)
  u16*   QKV = (u16*)(ws + (20ull << 20));   // [S][3072] bf16, 12 MiB
  float* Ob  = (float*)(ws + (20ull << 20)); // overlays QKV (after flash)
  u16*   Vtb = (u16*)(ws + (32ull << 20));   // [512][2048] bf16, 2 MiB

  k_pre<<<2048 + 1536, 256, 0, stream>>>(hidden, Hb, Wq, Wk, Wv, WT);
  k_gemm_mfma<<<dim3(24, 32), 256, 0, stream>>>(Hb, WT, QKV, QKVP, 2048, 1);
  k_transpose<<<dim3(32, 32), 256, 0, stream>>>(Wo, WoT, 2048, 2048);  // Hb dead
  k_norm_rope<<<dim3(S, 5), 256, 0, stream>>>(QKV, qsc, ksc, cosp, sinp);
  k_vt<<<dim3(32, 8), 256, 0, stream>>>(QKV, Vtb);
  k_flash<<<dim3(32, NH), 256, 0, stream>>>(QKV, Vtb, An);
  k_gemm_mfma<<<dim3(16, 32), 256, 0, stream>>>(An, WoT, Ob, 2048, 2048, 0);
  k_fnorm<<<S, 256, 0, stream>>>(Ob, lsc, out);
}

// Round 11
// 280.366 us; speedup vs baseline: 1.1924x; 1.0180x over previous
//
#include <hip/hip_runtime.h>

typedef unsigned short u16;
typedef unsigned int u32;

#define S 2048
#define HID 2048
#define NH 16
#define NKV 4
#define D 128
#define QKVP 3072  // QKV buffer pitch (Q|K|V concat per row)
// 1/sqrt(128) * log2(e): scores come out of QK^T already in log2 domain
#define QSCALE (0.08838834764831845f * 1.4426950408889634f)
#define NEG_INF -3.0e38f

typedef __attribute__((ext_vector_type(8))) short short8;  // 8 bf16 = 4 VGPRs
typedef __attribute__((ext_vector_type(4))) float f32x4;

__device__ __forceinline__ float bf2f(u16 u) {
  union { u32 i; float f; } c; c.i = ((u32)u) << 16; return c.f;
}
__device__ __forceinline__ u16 f2bf(float f) {
  union { float f; u32 i; } c; c.f = f;
  u32 x = c.i;
  u32 r = x + 0x7fffu + ((x >> 16) & 1u);  // RNE
  return (u16)(r >> 16);
}

#if __has_builtin(__builtin_amdgcn_exp2f)
__device__ __forceinline__ float exp2_hw(float x) { return __builtin_amdgcn_exp2f(x); }
#else
__device__ __forceinline__ float exp2_hw(float x) { return exp2f(x); }
#endif

// packed f32x2 -> bf16x2 (RNE), single VOP3
__device__ __forceinline__ u32 cvt_pk_bf16(float a, float b) {
  u32 r;
  asm("v_cvt_pk_bf16_f32 %0, %1, %2" : "=v"(r) : "v"(a), "v"(b));
  return r;
}

__device__ __forceinline__ void gload16(const u16* g, u16* l) {
  __builtin_amdgcn_global_load_lds(
      (const __attribute__((address_space(1))) u32*)g,
      (__attribute__((address_space(3))) u32*)l, 16, 0, 0);
}

// ------- transpose + convert body: src[K][N] f32 -> dst[N][K] bf16 ----------
__device__ __forceinline__ void transpose_body(const float* __restrict__ src,
                                               u16* __restrict__ dst,
                                               int N, int K, int nt, int kt,
                                               int t) {
  __shared__ float T[64][65];
#pragma unroll
  for (int it = 0; it < 4; ++it) {
    int r = it * 16 + (t >> 4), c = (t & 15) * 4;
    float4 v = *(const float4*)(src + (size_t)(kt + r) * N + nt + c);
    T[r][c] = v.x; T[r][c + 1] = v.y; T[r][c + 2] = v.z; T[r][c + 3] = v.w;
  }
  __syncthreads();
#pragma unroll
  for (int it = 0; it < 2; ++it) {
    int n = it * 32 + (t >> 3), k8 = (t & 7) * 8;
    ushort4 w0, w1;
    w0.x = f2bf(T[k8 + 0][n]); w0.y = f2bf(T[k8 + 1][n]);
    w0.z = f2bf(T[k8 + 2][n]); w0.w = f2bf(T[k8 + 3][n]);
    w1.x = f2bf(T[k8 + 4][n]); w1.y = f2bf(T[k8 + 5][n]);
    w1.z = f2bf(T[k8 + 6][n]); w1.w = f2bf(T[k8 + 7][n]);
    *(ushort4*)(dst + (size_t)(nt + n) * K + kt + k8) = w0;
    *(ushort4*)(dst + (size_t)(nt + n) * K + kt + k8 + 4) = w1;
  }
}

// ------- merged preprocessing: hidden f32->bf16 cvt + Wq|Wk|Wv transpose ----
__global__ __launch_bounds__(256) void k_pre(const float* __restrict__ hidden,
                                             u16* __restrict__ Hb,
                                             const float* __restrict__ Wq,
                                             const float* __restrict__ Wk,
                                             const float* __restrict__ Wv,
                                             u16* __restrict__ WT) {
  const int bx = blockIdx.x, t = threadIdx.x;
  if (bx < 2048) {  // cvt: 2048 blocks x 2048 elems
    int i = (bx * 256 + t) * 8;
    float4 v0 = *(const float4*)(hidden + i);
    float4 v1 = *(const float4*)(hidden + i + 4);
    ushort4 w0, w1;
    w0.x = f2bf(v0.x); w0.y = f2bf(v0.y); w0.z = f2bf(v0.z); w0.w = f2bf(v0.w);
    w1.x = f2bf(v1.x); w1.y = f2bf(v1.y); w1.z = f2bf(v1.z); w1.w = f2bf(v1.w);
    *(ushort4*)(Hb + i) = w0;
    *(ushort4*)(Hb + i + 4) = w1;
    return;
  }
  const int id = bx - 2048;            // 0..1535
  const int x = id % 48, y = id / 48;  // old dim3(48,32)
  const float* src; u16* dst; int N, nt;
  if (x < 32)      { src = Wq; dst = WT;                    N = 2048; nt = x * 64; }
  else if (x < 40) { src = Wk; dst = WT + 2048ull * 2048;   N = 512;  nt = (x - 32) * 64; }
  else             { src = Wv; dst = WT + 2560ull * 2048;   N = 512;  nt = (x - 40) * 64; }
  transpose_body(src, dst, N, 2048, nt, y * 64, t);
}

// ------- merged mid-stage: Wo transpose + RMSNorm/RoPE + V transpose --------
// Three mutually independent ops (disjoint data): Wo->WoT (Hb dead after QKV
// GEMM), norm+rope on QKV Q/K sections, V-section transpose to Vt. One launch
// removes 2 launch gaps + tail idle.
__global__ __launch_bounds__(256) void k_mid(const float* __restrict__ Wo,
                                             u16* __restrict__ WoT,
                                             u16* __restrict__ QKV,
                                             u16* __restrict__ Vt,
                                             const float* __restrict__ qsc,
                                             const float* __restrict__ ksc,
                                             const float* __restrict__ cosp,
                                             const float* __restrict__ sinp) {
  const int bi = blockIdx.x, t = threadIdx.x;
  if (bi < 10240) {  // ---- RMSNorm + RoPE, one WAVE per (s,head) row ----
    const int s = bi & 2047;
    const int w = t >> 6, lane = t & 63;
    const int hh = (bi >> 11) * 4 + w;
    u16* row; const float* sc; float scale;
    if (hh < NH) { row = QKV + (size_t)s * QKVP + hh * D;               sc = qsc; scale = QSCALE; }
    else         { row = QKV + (size_t)s * QKVP + 2048 + (hh - NH) * D; sc = ksc; scale = 1.0f; }
    const int d0 = lane * 2;
    u32 pr = *(const u32*)(row + d0);
    float x0 = bf2f((u16)(pr & 0xffffu)), x1 = bf2f((u16)(pr >> 16));
    float v = x0 * x0 + x1 * x1;
#pragma unroll
    for (int o = 32; o; o >>= 1) v += __shfl_xor(v, o, 64);
    float rinv = rsqrtf(v * (1.0f / 128.0f) + 1e-6f) * scale;
    float xn0 = x0 * rinv * sc[d0], xn1 = x1 * rinv * sc[d0 + 1];
    float p0 = __shfl_xor(xn0, 32, 64);
    float p1 = __shfl_xor(xn1, 32, 64);
    float sgn = (lane < 32) ? -1.f : 1.f;
    float2 c  = *(const float2*)(cosp + (size_t)s * D + d0);
    float2 sn = *(const float2*)(sinp + (size_t)s * D + d0);
    float o0 = xn0 * c.x + sgn * p0 * sn.x;
    float o1 = xn1 * c.y + sgn * p1 * sn.y;
    *(u32*)(row + d0) = cvt_pk_bf16(o0, o1);
    return;
  }
  if (bi < 11264) {  // ---- Wo transpose: 1024 blocks (32 x 32) ----
    const int id = bi - 10240;
    transpose_body(Wo, WoT, 2048, 2048, (id & 31) * 64, (id >> 5) * 64, t);
    return;
  }
  // ---- V transpose: 256 blocks (32 x 8): QKV[s][2560+gd] -> Vt[gd][s] ----
  {
    const int id = bi - 11264;
    const int s0 = (id & 31) * 64, d0 = (id >> 5) * 64;
    __shared__ u16 T[64][66];
#pragma unroll
    for (int it = 0; it < 4; ++it) {
      int r = it * 16 + (t >> 4), c = (t & 15) * 4;
      ushort4 v = *(const ushort4*)(QKV + (size_t)(s0 + r) * QKVP + 2560 + d0 + c);
      T[r][c] = v.x; T[r][c + 1] = v.y; T[r][c + 2] = v.z; T[r][c + 3] = v.w;
    }
    __syncthreads();
#pragma unroll
    for (int it = 0; it < 4; ++it) {
      int dd = it * 16 + (t >> 4), sc = (t & 15) * 4;
      ushort4 w;
      w.x = T[sc + 0][dd]; w.y = T[sc + 1][dd];
      w.z = T[sc + 2][dd]; w.w = T[sc + 3][dd];
      *(ushort4*)(Vt + (size_t)(d0 + dd) * S + s0 + sc) = w;
    }
  }
}

// ------- MFMA GEMM: BM=64 x BN=128, BK=64, XOR swizzle, READS-FIRST loop ----
// Key fix: frag ds_reads now precede the STAGE(next) DMA issue. With STAGE
// first, the compiler cannot disambiguate As[cur] vs As[cur^1] (runtime
// index) and inserts a conservative s_waitcnt vmcnt(0) BEFORE the ds_reads,
// draining the just-issued prefetch at full latency every K-step (zero
// pipeline). Reads-first: zero outstanding VMEM at loop top (barrier drained
// it) -> no stall; the DMA then flies under 16 MFMAs + the barrier.
__global__ __launch_bounds__(256) void k_gemm_mfma(const u16* __restrict__ A,
                                                   const u16* __restrict__ BT,
                                                   void* __restrict__ Cout,
                                                   int N, int K, int out_bf16) {
  __shared__ __align__(16) u16 As[2][64 * 64];
  __shared__ __align__(16) u16 Bs[2][128 * 64];
  const int t = threadIdx.x, w = t >> 6, lane = t & 63;
  const int l15 = lane & 15, quad = lane >> 4;
  const int m0 = blockIdx.y * 64, n0 = blockIdx.x * 128;

  const int srow = lane >> 3;                       // 0..7 within issue
  const int schunk = (lane & 7) ^ srow;             // pre-swizzled source chunk
  const u16* Agb = A + (size_t)(m0 + w * 8 + srow) * K + schunk * 8;
  const u16* Bgb = BT + (size_t)(n0 + w * 8 + srow) * K + schunk * 8;

  f32x4 acc[4][2];
#pragma unroll
  for (int i = 0; i < 4; ++i)
#pragma unroll
    for (int j = 0; j < 2; ++j) acc[i][j] = (f32x4){0.f, 0.f, 0.f, 0.f};

  auto STAGE = [&](int k0, int b) {
#pragma unroll
    for (int it = 0; it < 2; ++it)
      gload16(Agb + (size_t)it * 32 * K + k0, &As[b][(w * 8 + it * 32) * 64]);
#pragma unroll
    for (int it = 0; it < 4; ++it)
      gload16(Bgb + (size_t)it * 32 * K + k0, &Bs[b][(w * 8 + it * 32) * 64]);
  };

  STAGE(0, 0);
  __syncthreads();  // buf0 ready
  int cur = 0;
  for (int k0 = 0; k0 < K; k0 += 64) {
    // frag reads FIRST: no outstanding VMEM at entry -> no conservative drain
    short8 af[4][2], bf[2][2];
#pragma unroll
    for (int k2 = 0; k2 < 2; ++k2) {
      int ch = (k2 * 4 + quad) ^ (l15 & 7);
#pragma unroll
      for (int i = 0; i < 4; ++i)
        af[i][k2] = *(const short8*)&As[cur][(i * 16 + l15) * 64 + ch * 8];
#pragma unroll
      for (int j = 0; j < 2; ++j)
        bf[j][k2] = *(const short8*)&Bs[cur][(w * 32 + j * 16 + l15) * 64 + ch * 8];
    }

    if (k0 + 64 < K) STAGE(k0 + 64, cur ^ 1);  // DMA flies under the MFMAs

#pragma unroll
    for (int k2 = 0; k2 < 2; ++k2)
#pragma unroll
      for (int i = 0; i < 4; ++i)
#pragma unroll
        for (int j = 0; j < 2; ++j)
          acc[i][j] = __builtin_amdgcn_mfma_f32_16x16x32_bf16(af[i][k2], bf[j][k2], acc[i][j], 0, 0, 0);

    __syncthreads();  // drains prefetch + all waves done reading cur
    cur ^= 1;
  }

  if (out_bf16) {
    u16* C = (u16*)Cout;
#pragma unroll
    for (int i = 0; i < 4; ++i)
#pragma unroll
      for (int j = 0; j < 2; ++j) {
        int col = n0 + w * 32 + j * 16 + l15;
#pragma unroll
        for (int r = 0; r < 4; ++r)
          C[(size_t)(m0 + i * 16 + quad * 4 + r) * N + col] = f2bf(acc[i][j][r]);
      }
  } else {
    float* C = (float*)Cout;
#pragma unroll
    for (int i = 0; i < 4; ++i)
#pragma unroll
      for (int j = 0; j < 2; ++j) {
        int col = n0 + w * 32 + j * 16 + l15;
#pragma unroll
        for (int r = 0; r < 4; ++r)
          C[(size_t)(m0 + i * 16 + quad * 4 + r) * N + col] = acc[i][j][r];
      }
  }
}

// ---------------- flash attention (R10-frozen) ------------------------------
#define KP 128   // K LDS row pitch (u16), unpadded (DMA requirement)
#define PTP 72   // P pitch (u16): b64-write / b128-read aligned

__global__ __launch_bounds__(256) void k_flash(const u16* __restrict__ QKV,
                                               const u16* __restrict__ Vt,
                                               u16* __restrict__ O) {
  const int h = blockIdx.y, g = h >> 2;
  const int qt = (h < 8) ? (31 - (int)blockIdx.x) : (int)blockIdx.x;
  const int t = threadIdx.x;
  const int w = t >> 6, lane = t & 63, l15 = lane & 15, quad = lane >> 4;

  __shared__ __align__(16) u16 Klds[2][64 * KP];
  __shared__ __align__(16) u16 Vlds[128 * 64];     // [d][key], XOR-swizzled
  __shared__ __align__(16) u16 Pt[4][16 * PTP];    // [qcol][key] per wave

  const int qbase = qt * 64 + w * 16;
  const int qrow = qbase + l15;

  short8 qf[4];
  {
    const u16* qp = QKV + (size_t)qrow * QKVP + h * D + quad * 8;
#pragma unroll
    for (int c = 0; c < 4; ++c) qf[c] = *(const short8*)(qp + c * 32);
  }

  float m = NEG_INF, l = 0.f;
  f32x4 oacc[8];
#pragma unroll
  for (int nc = 0; nc < 8; ++nc) oacc[nc] = (f32x4){0.f, 0.f, 0.f, 0.f};

  const int nt = qt + 1;
  const int dd = t >> 3, cc = t & 7;  // V staging coords

  auto KLOAD = [&](int j0, int b) {  // DMA 4 rows per wave per issue
#pragma unroll
    for (int it = 0; it < 4; ++it) {
      int rl = w * 16 + it * 4 + quad;                 // tile-local key row
      int gchunk = (lane & 15) ^ (rl & 7);             // source swizzle
      const u16* gp = QKV + (size_t)(j0 + rl) * QKVP + 2048 + g * D + gchunk * 8;
      gload16(gp, &Klds[b][(w * 16 + it * 4) * KP]);
    }
  };
  auto VLOAD = [&](int j0, uint4* vr) {
#pragma unroll
    for (int it = 0; it < 4; ++it)
      vr[it] = *(const uint4*)(Vt + (size_t)(g * D + dd + it * 32) * S + j0 + cc * 8);
  };
  auto VWRITE = [&](uint4* vr) {
#pragma unroll
    for (int it = 0; it < 4; ++it) {
      int d = dd + it * 32;
      *(uint4*)&Vlds[d * 64 + ((cc ^ (d & 7)) * 8)] = vr[it];
    }
  };
  auto QKT = [&](int b, f32x4* sa) {
#pragma unroll
    for (int sub = 0; sub < 4; ++sub) {
      f32x4 acc = {0.f, 0.f, 0.f, 0.f};
#pragma unroll
      for (int c = 0; c < 4; ++c) {
        int ch = (c * 4 + quad) ^ (l15 & 7);  // undo source swizzle
        short8 kf = *(const short8*)&Klds[b][(sub * 16 + l15) * KP + ch * 8];
        acc = __builtin_amdgcn_mfma_f32_16x16x32_bf16(kf, qf[c], acc, 0, 0, 0);
      }
      sa[sub] = acc;
    }
  };
  auto SMPV = [&](int jt, f32x4* sa) {
    const int j0 = jt * 64;
    if (jt == nt - 1) {  // causal mask, diagonal tile only
#pragma unroll
      for (int sub = 0; sub < 4; ++sub) {
        int keyb = j0 + sub * 16 + quad * 4;
#pragma unroll
        for (int r = 0; r < 4; ++r)
          if (keyb + r > qrow) sa[sub][r] = NEG_INF;
      }
    }
    float tmax = sa[0][0];
#pragma unroll
    for (int sub = 0; sub < 4; ++sub)
#pragma unroll
      for (int r = 0; r < 4; ++r) tmax = fmaxf(tmax, sa[sub][r]);
    tmax = fmaxf(tmax, __shfl_xor(tmax, 16, 64));
    tmax = fmaxf(tmax, __shfl_xor(tmax, 32, 64));
    float mn = fmaxf(m, tmax);
    float alpha = exp2_hw(m - mn);
    m = mn;
    float rs = 0.f;
#pragma unroll
    for (int sub = 0; sub < 4; ++sub) {
      float p0 = exp2_hw(sa[sub][0] - m);
      float p1 = exp2_hw(sa[sub][1] - m);
      float p2 = exp2_hw(sa[sub][2] - m);
      float p3 = exp2_hw(sa[sub][3] - m);
      rs += (p0 + p1) + (p2 + p3);
      u32 lo = cvt_pk_bf16(p0, p1);
      u32 hi = cvt_pk_bf16(p2, p3);
      *(uint2*)&Pt[w][l15 * PTP + sub * 16 + quad * 4] = make_uint2(lo, hi);
    }
    rs += __shfl_xor(rs, 16, 64);
    rs += __shfl_xor(rs, 32, 64);
    l = l * alpha + rs;
#pragma unroll
    for (int nc = 0; nc < 8; ++nc) {
      oacc[nc][0] *= alpha; oacc[nc][1] *= alpha;
      oacc[nc][2] *= alpha; oacc[nc][3] *= alpha;
    }
#pragma unroll
    for (int kc = 0; kc < 2; ++kc) {
      short8 pf = *(const short8*)&Pt[w][l15 * PTP + kc * 32 + quad * 8];
#pragma unroll
      for (int nc = 0; nc < 8; ++nc) {
        int d = nc * 16 + l15;
        short8 vf = *(const short8*)&Vlds[d * 64 + (((kc * 4 + quad) ^ (d & 7)) * 8)];
        oacc[nc] = __builtin_amdgcn_mfma_f32_16x16x32_bf16(vf, pf, oacc[nc], 0, 0, 0);
      }
    }
  };

  uint4 vrA[4], vrB[4];
  f32x4 sa[4];
  KLOAD(0, 0);
  VLOAD(0, vrA);
  for (int jt = 0; jt < nt; jt += 2) {
    __syncthreads();                       // drains K(jt) DMA + all VMEM
    VWRITE(vrA);
    __syncthreads();                       // V(jt) visible
    QKT(0, sa);                            // no outstanding VMEM -> no stall
    if (jt + 1 < nt) { KLOAD((jt + 1) * 64, 1); VLOAD((jt + 1) * 64, vrB); }
    SMPV(jt, sa);                          // covers prefetch latency
    if (jt + 1 < nt) {
      __syncthreads();                     // drains K(jt+1)+V(jt+1), covered
      VWRITE(vrB);
      __syncthreads();
      QKT(1, sa);
      if (jt + 2 < nt) { KLOAD((jt + 2) * 64, 0); VLOAD((jt + 2) * 64, vrA); }
      SMPV(jt + 1, sa);
    }
  }

  // ---- epilogue: O[q][d] = O^T / l ----
  float inv = 1.0f / l;
  u16* orow = O + (size_t)qrow * HID + h * D;
#pragma unroll
  for (int nc = 0; nc < 8; ++nc) {
    ushort4 wv;
    wv.x = f2bf(oacc[nc][0] * inv); wv.y = f2bf(oacc[nc][1] * inv);
    wv.z = f2bf(oacc[nc][2] * inv); wv.w = f2bf(oacc[nc][3] * inv);
    *(ushort4*)(orow + nc * 16 + quad * 4) = wv;
  }
}

// ---------------- final RMSNorm over HIDDEN=2048 ----------------------------
__device__ __forceinline__ float blockSum256(float v, float* red, int t) {
#pragma unroll
  for (int o = 32; o; o >>= 1) v += __shfl_xor(v, o, 64);
  if ((t & 63) == 0) red[t >> 6] = v;
  __syncthreads();
  v = red[0] + red[1] + red[2] + red[3];
  __syncthreads();
  return v;
}

__global__ __launch_bounds__(256) void k_fnorm(const float* __restrict__ X,
                                               const float* __restrict__ sc,
                                               float* __restrict__ out) {
  const int s = blockIdx.x, t = threadIdx.x;
  const float* row = X + (size_t)s * HID;
  float4 r0 = *(const float4*)(row + t * 8);
  float4 r1 = *(const float4*)(row + t * 8 + 4);
  float x[8] = {r0.x, r0.y, r0.z, r0.w, r1.x, r1.y, r1.z, r1.w};
  float ss = 0.f;
#pragma unroll
  for (int ii = 0; ii < 8; ++ii) ss += x[ii] * x[ii];
  __shared__ float red[4];
  float tot = blockSum256(ss, red, t);
  float rinv = rsqrtf(tot * (1.0f / 2048.0f) + 1e-6f);
  float4 s0 = *(const float4*)(sc + t * 8);
  float4 s1 = *(const float4*)(sc + t * 8 + 4);
  float4 w0 = make_float4(x[0] * rinv * s0.x, x[1] * rinv * s0.y,
                          x[2] * rinv * s0.z, x[3] * rinv * s0.w);
  float4 w1 = make_float4(x[4] * rinv * s1.x, x[5] * rinv * s1.y,
                          x[6] * rinv * s1.z, x[7] * rinv * s1.w);
  *(float4*)(out + (size_t)s * HID + t * 8) = w0;
  *(float4*)(out + (size_t)s * HID + t * 8 + 4) = w1;
}

extern "C" void kernel_launch(void* const* d_in, const int* in_sizes, int n_in,
                              void* d_out, int out_size, void* d_ws, size_t ws_size,
                              hipStream_t stream) {
  const float* hidden = (const float*)d_in[0];
  const float* cosp   = (const float*)d_in[1];
  const float* sinp   = (const float*)d_in[2];
  const float* Wq     = (const float*)d_in[3];
  const float* Wk     = (const float*)d_in[4];
  const float* Wv     = (const float*)d_in[5];
  const float* Wo     = (const float*)d_in[6];
  const float* qsc    = (const float*)d_in[7];
  const float* ksc    = (const float*)d_in[8];
  const float* lsc    = (const float*)d_in[9];
  float* out = (float*)d_out;

  char* ws = (char*)d_ws;
  u16*   Hb  = (u16*)(ws);                   // [S][HID] bf16, 8 MiB
  u16*   WoT = (u16*)(ws);                   // overlays Hb (after QKV GEMM)
  u16*   WT  = (u16*)(ws + (8ull << 20));    // [3072][2048] bf16, 12 MiB
  u16*   An  = (u16*)(ws + (8ull << 20));    // overlays WT (after QKV GEMM)
  u16*   QKV = (u16*)(ws + (20ull << 20));   // [S][3072] bf16, 12 MiB
  float* Ob  = (float*)(ws + (20ull << 20)); // overlays QKV (after flash)
  u16*   Vtb = (u16*)(ws + (32ull << 20));   // [512][2048] bf16, 2 MiB

  k_pre<<<2048 + 1536, 256, 0, stream>>>(hidden, Hb, Wq, Wk, Wv, WT);
  k_gemm_mfma<<<dim3(24, 32), 256, 0, stream>>>(Hb, WT, QKV, QKVP, 2048, 1);
  k_mid<<<11520, 256, 0, stream>>>(Wo, WoT, QKV, Vtb, qsc, ksc, cosp, sinp);
  k_flash<<<dim3(32, NH), 256, 0, stream>>>(QKV, Vtb, An);
  k_gemm_mfma<<<dim3(16, 32), 256, 0, stream>>>(An, WoT, Ob, 2048, 2048, 0);
  k_fnorm<<<S, 256, 0, stream>>>(Ob, lsc, out);
}